// Round 1
// baseline (1927.505 us; speedup 1.0000x reference)
//
#include <hip/hip_runtime.h>
#include <hip/hip_bf16.h>

constexpr int N_  = 20000;
constexpr int E_  = 320000;
constexpr int T_  = 24;
constexpr float NEG_ = 0.2f;
constexpr float EPS_ = 1e-5f;

// ---------- edge_index accessors (int32 vs int64 runtime-detected) ----------
__device__ __forceinline__ int esrc(const int* __restrict__ p, int e, int f64) {
    return f64 ? p[4 * e] : p[2 * e];
}
__device__ __forceinline__ int edst(const int* __restrict__ p, int e, int f64) {
    return f64 ? p[4 * e + 2] : p[2 * e + 1];
}

// monotone float<->uint transform for atomicMax on floats
__device__ __forceinline__ unsigned fxform(float f) {
    unsigned u = __float_as_uint(f);
    return (u & 0x80000000u) ? ~u : (u | 0x80000000u);
}
__device__ __forceinline__ float funxform(unsigned u) {
    return (u & 0x80000000u) ? __uint_as_float(u ^ 0x80000000u) : __uint_as_float(~u);
}

// ---------- detect int64 vs int32 edge_index ----------
__global__ void k_detect(const int* __restrict__ idx, int* __restrict__ flag) {
    int v = idx[2 * threadIdx.x + 1];          // odd 32-bit words of first 64 elements
    unsigned long long b = __ballot(v != 0);
    if (threadIdx.x == 0) flag[0] = (b == 0ULL) ? 1 : 0;   // all-zero -> int64
}

// ---------- P[k][h] = sum_c W_edge[k, h*64+c] * att_edge[h, c] ----------
__global__ void k_P(const float* __restrict__ W_edge, const float* __restrict__ att_edge,
                    float* __restrict__ P) {
    int t = threadIdx.x;            // 64 threads
    int k = t >> 2, h = t & 3;
    float s = 0.f;
    for (int c = 0; c < 64; ++c) s += W_edge[k * 256 + h * 64 + c] * att_edge[h * 64 + c];
    P[k * 4 + h] = s;
}

// ---------- per-node: xh = x @ W_lin ; a_src, a_dst ----------
__global__ __launch_bounds__(256) void k_node(
    const float* __restrict__ x, const float* __restrict__ W_lin,
    const float* __restrict__ att_s, const float* __restrict__ att_d,
    float* __restrict__ xh, float* __restrict__ asrc, float* __restrict__ adst) {
    int n = blockIdx.x, j = threadIdx.x;
    __shared__ float xr[64];
    if (j < 64) xr[j] = x[n * 64 + j];
    __syncthreads();
    float acc = 0.f;
#pragma unroll
    for (int k = 0; k < 64; ++k) acc += xr[k] * W_lin[k * 256 + j];
    xh[(long)n * 256 + j] = acc;
    float vs = acc * att_s[j], vd = acc * att_d[j];
#pragma unroll
    for (int m = 32; m >= 1; m >>= 1) { vs += __shfl_xor(vs, m); vd += __shfl_xor(vd, m); }
    if ((j & 63) == 0) { int h = j >> 6; asrc[n * 4 + h] = vs; adst[n * 4 + h] = vd; }
}

// ---------- deg + mean_attr accumulation ----------
__global__ void k_edge_accum(const int* __restrict__ idx, const int* __restrict__ flag,
                             const float* __restrict__ ea,
                             float* __restrict__ deg, float* __restrict__ mattr) {
    int e = blockIdx.x * 256 + threadIdx.x;
    if (e >= E_) return;
    int f64 = flag[0];
    int d = edst(idx, e, f64);
    atomicAdd(&deg[d], 1.0f);
    const float4* ep = (const float4*)(ea + (long)e * 16);
    float4 a = ep[0], b = ep[1], c = ep[2], dd = ep[3];
    float* mp = mattr + (long)d * 16;
    atomicAdd(mp + 0, a.x);  atomicAdd(mp + 1, a.y);  atomicAdd(mp + 2, a.z);  atomicAdd(mp + 3, a.w);
    atomicAdd(mp + 4, b.x);  atomicAdd(mp + 5, b.y);  atomicAdd(mp + 6, b.z);  atomicAdd(mp + 7, b.w);
    atomicAdd(mp + 8, c.x);  atomicAdd(mp + 9, c.y);  atomicAdd(mp + 10, c.z); atomicAdd(mp + 11, c.w);
    atomicAdd(mp + 12, dd.x);atomicAdd(mp + 13, dd.y);atomicAdd(mp + 14, dd.z);atomicAdd(mp + 15, dd.w);
}

__global__ void k_meandiv(float* __restrict__ mattr, const float* __restrict__ deg) {
    int i = blockIdx.x * 256 + threadIdx.x;
    if (i >= N_ * 16) return;
    mattr[i] /= fmaxf(deg[i >> 4], 1.0f);
}

// ---------- alpha = leaky_relu(a_src[src]+a_dst[dst]+a_edge) ; segment max ----------
__global__ void k_alpha(const int* __restrict__ idx, const int* __restrict__ flag,
                        const float* __restrict__ ea, const float* __restrict__ mattr,
                        const float* __restrict__ P,
                        const float* __restrict__ asrc, const float* __restrict__ adst,
                        float* __restrict__ alpha, unsigned* __restrict__ amax) {
    int e = blockIdx.x * 256 + threadIdx.x;
    if (e >= E_ + N_) return;
    int f64 = flag[0];
    int s, d;
    const float* ep;
    if (e < E_) { s = esrc(idx, e, f64); d = edst(idx, e, f64); ep = ea + (long)e * 16; }
    else        { s = d = e - E_;        ep = mattr + (long)(e - E_) * 16; }
    float ae[4] = {0.f, 0.f, 0.f, 0.f};
#pragma unroll
    for (int k = 0; k < 16; ++k) {
        float v = ep[k];
#pragma unroll
        for (int h = 0; h < 4; ++h) ae[h] += v * P[k * 4 + h];
    }
#pragma unroll
    for (int h = 0; h < 4; ++h) {
        float al = asrc[s * 4 + h] + adst[d * 4 + h] + ae[h];
        al = (al > 0.f) ? al : NEG_ * al;
        alpha[(long)e * 4 + h] = al;
        atomicMax(&amax[d * 4 + h], fxform(al));
    }
}

// ---------- ex = exp(alpha - amax[dst]) ; segment sum ----------
__global__ void k_ex(const int* __restrict__ idx, const int* __restrict__ flag,
                     float* __restrict__ alpha, const unsigned* __restrict__ amax,
                     float* __restrict__ denom) {
    long i = (long)blockIdx.x * 256 + threadIdx.x;
    if (i >= (long)(E_ + N_) * 4) return;
    int e = (int)(i >> 2), h = (int)(i & 3);
    int f64 = flag[0];
    int d = (e < E_) ? edst(idx, e, f64) : (e - E_);
    float am = funxform(amax[d * 4 + h]);
    if (!isfinite(am)) am = 0.f;
    float ex = __expf(alpha[i] - am);
    alpha[i] = ex;
    atomicAdd(&denom[d * 4 + h], ex);
}

// ---------- weighted scatter: x1[d,c] += sum_h attn * xh[s,h,c] ----------
__global__ __launch_bounds__(256) void k_scatter(
    const int* __restrict__ idx, const int* __restrict__ flag,
    const float* __restrict__ ex, const float* __restrict__ denom,
    const float* __restrict__ xh, float* __restrict__ x1) {
    int e = blockIdx.x * 4 + (threadIdx.x >> 6);
    int c = threadIdx.x & 63;
    if (e >= E_ + N_) return;
    int f64 = flag[0];
    int s, d;
    if (e < E_) { s = esrc(idx, e, f64); d = edst(idx, e, f64); }
    else        { s = d = e - E_; }
    float acc = 0.f;
#pragma unroll
    for (int h = 0; h < 4; ++h) {
        float at = ex[(long)e * 4 + h] / (denom[d * 4 + h] + 1e-16f);
        acc += at * xh[(long)s * 256 + h * 64 + c];
    }
    atomicAdd(&x1[(long)d * 64 + c], acc);
}

// ---------- finalize x1 (mean over heads + bias) and BN stats ----------
__global__ __launch_bounds__(256) void k_x1stats(
    float* __restrict__ x1, const float* __restrict__ bias, float* __restrict__ bnsum) {
    int c = threadIdx.x & 63, r = threadIdx.x >> 6;
    float s = 0.f, s2 = 0.f;
    for (int n = blockIdx.x * 4 + r; n < N_; n += gridDim.x * 4) {
        float v = x1[(long)n * 64 + c] * 0.25f + bias[c];
        x1[(long)n * 64 + c] = v;
        s += v; s2 += v * v;
    }
    __shared__ float red[4][128];
    red[r][c] = s; red[r][64 + c] = s2;
    __syncthreads();
    if (r == 0) {
        float ts = red[0][c] + red[1][c] + red[2][c] + red[3][c];
        float t2 = red[0][64 + c] + red[1][64 + c] + red[2][64 + c] + red[3][64 + c];
        atomicAdd(&bnsum[c], ts);
        atomicAdd(&bnsum[64 + c], t2);
    }
}

__global__ void k_bnfin(const float* __restrict__ bnsum, const float* __restrict__ gamma,
                        const float* __restrict__ beta, float* __restrict__ bnp) {
    int c = threadIdx.x;
    float mu = bnsum[c] / (float)N_;
    float var = bnsum[64 + c] / (float)N_ - mu * mu;
    float sc = gamma[c] * rsqrtf(var + EPS_);
    bnp[c] = sc;
    bnp[64 + c] = beta[c] - mu * sc;
}

// ---------- LSTM: one wave per node, h unit per lane ----------
__global__ __launch_bounds__(256) void k_lstm(
    const float* __restrict__ xdyn, const float* __restrict__ W_ih,
    const float* __restrict__ W_hh, const float* __restrict__ b_ih,
    const float* __restrict__ b_hh, float* __restrict__ hlast) {
    __shared__ float4 W4[64 * 64];   // [m][l] -> (gate0..3 rows g*64+l, col m)
    __shared__ float  WT[8 * 256];   // [k][j]
    __shared__ float  hb[4][64];
    int t = threadIdx.x;
    for (int i = 0; i < 64; ++i) {
        int id = i * 256 + t;        // element of W_hh in row-major [j][m]
        int j = id >> 6, m = id & 63;
        ((float*)W4)[(m * 64 + (j & 63)) * 4 + (j >> 6)] = W_hh[id];
    }
    for (int k = 0; k < 8; ++k) WT[k * 256 + t] = W_ih[t * 8 + k];
    int w = t >> 6, l = t & 63;
    int n = blockIdx.x * 4 + w;
    float bg0 = b_ih[l] + b_hh[l];
    float bg1 = b_ih[64 + l] + b_hh[64 + l];
    float bg2 = b_ih[128 + l] + b_hh[128 + l];
    float bg3 = b_ih[192 + l] + b_hh[192 + l];
    float h = 0.f, cc = 0.f;
    hb[w][l] = 0.f;
    __syncthreads();
    const float* xp = xdyn + (long)n * T_ * 8;
    for (int st = 0; st < T_; ++st) {
        float g0 = bg0, g1 = bg1, g2 = bg2, g3 = bg3;
#pragma unroll
        for (int k = 0; k < 8; ++k) {
            float xk = xp[st * 8 + k];
            g0 += xk * WT[k * 256 + l];
            g1 += xk * WT[k * 256 + 64 + l];
            g2 += xk * WT[k * 256 + 128 + l];
            g3 += xk * WT[k * 256 + 192 + l];
        }
#pragma unroll
        for (int m = 0; m < 64; ++m) {
            float hm = hb[w][m];
            float4 wv = W4[m * 64 + l];
            g0 += hm * wv.x; g1 += hm * wv.y; g2 += hm * wv.z; g3 += hm * wv.w;
        }
        float ig = 1.f / (1.f + __expf(-g0));
        float fg = 1.f / (1.f + __expf(-g1));
        float gg = tanhf(g2);
        float og = 1.f / (1.f + __expf(-g3));
        cc = fg * cc + ig * gg;
        h = og * tanhf(cc);
        __syncthreads();
        hb[w][l] = h;
        __syncthreads();
    }
    hlast[(long)n * 64 + l] = h;
}

// ---------- head: BN-relu(x1) ++ h_last -> hidden -> out ----------
__global__ __launch_bounds__(256) void k_head(
    const float* __restrict__ x1, const float* __restrict__ hlast,
    const float* __restrict__ bnp, const float* __restrict__ W_hid,
    const float* __restrict__ b_hid, const float* __restrict__ W_out,
    const float* __restrict__ b_out, float* __restrict__ out) {
    int n = blockIdx.x * 256 + threadIdx.x;
    if (n >= N_) return;
    float comb[128];
#pragma unroll
    for (int i = 0; i < 64; ++i)
        comb[i] = fmaxf(x1[(long)n * 64 + i] * bnp[i] + bnp[64 + i], 0.f);
#pragma unroll
    for (int i = 0; i < 64; ++i) comb[64 + i] = hlast[(long)n * 64 + i];
    float o = b_out[0];
    for (int j = 0; j < 32; ++j) {
        float a = b_hid[j];
#pragma unroll
        for (int i = 0; i < 128; ++i) a += comb[i] * W_hid[i * 32 + j];
        o += fmaxf(a, 0.f) * W_out[j];
    }
    out[n] = o;
}

extern "C" void kernel_launch(void* const* d_in, const int* in_sizes, int n_in,
                              void* d_out, int out_size, void* d_ws, size_t ws_size,
                              hipStream_t stream) {
    const float* x_node   = (const float*)d_in[0];
    const float* ea       = (const float*)d_in[1];
    const float* xdyn     = (const float*)d_in[2];
    const int*   eidx     = (const int*)d_in[3];
    const float* W_lin    = (const float*)d_in[4];
    const float* W_edge   = (const float*)d_in[5];
    const float* att_src  = (const float*)d_in[6];
    const float* att_dst  = (const float*)d_in[7];
    const float* att_edge = (const float*)d_in[8];
    const float* gat_bias = (const float*)d_in[9];
    const float* bn_gamma = (const float*)d_in[10];
    const float* bn_beta  = (const float*)d_in[11];
    const float* W_ih     = (const float*)d_in[12];
    const float* W_hh     = (const float*)d_in[13];
    const float* b_ih     = (const float*)d_in[14];
    const float* b_hh     = (const float*)d_in[15];
    const float* W_hid    = (const float*)d_in[16];
    const float* b_hid    = (const float*)d_in[17];
    const float* W_out    = (const float*)d_in[18];
    const float* b_out    = (const float*)d_in[19];
    float* out = (float*)d_out;

    char* ws = (char*)d_ws;
    size_t off = 0;
    auto alloc = [&](size_t bytes) -> void* {
        void* p = ws + off;
        off = (off + bytes + 255) & ~(size_t)255;
        return p;
    };
    int*      flag  = (int*)alloc(4);
    float*    P     = (float*)alloc(64 * 4);
    float*    bnp   = (float*)alloc(128 * 4);
    char*     zs    = ws + off;                       // ---- zero region start
    float*    bnsum = (float*)alloc(128 * 4);
    float*    deg   = (float*)alloc((size_t)N_ * 4);
    float*    mattr = (float*)alloc((size_t)N_ * 16 * 4);
    unsigned* amax  = (unsigned*)alloc((size_t)N_ * 4 * 4);
    float*    denom = (float*)alloc((size_t)N_ * 4 * 4);
    float*    x1    = (float*)alloc((size_t)N_ * 64 * 4);
    size_t zbytes = (size_t)((ws + off) - zs);        // ---- zero region end
    float*    alpha = (float*)alloc((size_t)(E_ + N_) * 4 * 4);
    float*    xh    = (float*)alloc((size_t)N_ * 256 * 4);
    float*    asrc  = (float*)alloc((size_t)N_ * 4 * 4);
    float*    adst  = (float*)alloc((size_t)N_ * 4 * 4);
    float*    hlast = (float*)alloc((size_t)N_ * 64 * 4);
    (void)ws_size; (void)in_sizes; (void)n_in; (void)out_size;

    hipMemsetAsync(zs, 0, zbytes, stream);
    k_detect<<<1, 64, 0, stream>>>(eidx, flag);
    k_P<<<1, 64, 0, stream>>>(W_edge, att_edge, P);
    k_node<<<N_, 256, 0, stream>>>(x_node, W_lin, att_src, att_dst, xh, asrc, adst);
    k_edge_accum<<<(E_ + 255) / 256, 256, 0, stream>>>(eidx, flag, ea, deg, mattr);
    k_meandiv<<<(N_ * 16 + 255) / 256, 256, 0, stream>>>(mattr, deg);
    k_alpha<<<(E_ + N_ + 255) / 256, 256, 0, stream>>>(eidx, flag, ea, mattr, P, asrc, adst, alpha, amax);
    k_ex<<<(int)(((long)(E_ + N_) * 4 + 255) / 256), 256, 0, stream>>>(eidx, flag, alpha, amax, denom);
    k_scatter<<<(E_ + N_ + 3) / 4, 256, 0, stream>>>(eidx, flag, alpha, denom, xh, x1);
    k_x1stats<<<128, 256, 0, stream>>>(x1, gat_bias, bnsum);
    k_bnfin<<<1, 64, 0, stream>>>(bnsum, bn_gamma, bn_beta, bnp);
    k_lstm<<<N_ / 4, 256, 0, stream>>>(xdyn, W_ih, W_hh, b_ih, b_hh, hlast);
    k_head<<<(N_ + 255) / 256, 256, 0, stream>>>(x1, hlast, bnp, W_hid, b_hid, W_out, b_out, out);
}

// Round 3
// 1197.671 us; speedup vs baseline: 1.6094x; 1.6094x over previous
//
#include <hip/hip_runtime.h>
#include <hip/hip_bf16.h>

constexpr int N_  = 20000;
constexpr int E_  = 320000;
constexpr int T_  = 24;
constexpr float NEG_ = 0.2f;
constexpr float EPS_ = 1e-5f;
constexpr int NB_ = 4;                  // nodes per lane in LSTM

// ---------- edge_index accessors (int32 vs int64 runtime-detected) ----------
__device__ __forceinline__ int esrc(const int* __restrict__ p, int e, int f64) {
    return f64 ? p[4 * e] : p[2 * e];
}
__device__ __forceinline__ int edst(const int* __restrict__ p, int e, int f64) {
    return f64 ? p[4 * e + 2] : p[2 * e + 1];
}

// monotone float<->uint transform for atomicMax on floats
__device__ __forceinline__ unsigned fxform(float f) {
    unsigned u = __float_as_uint(f);
    return (u & 0x80000000u) ? ~u : (u | 0x80000000u);
}
__device__ __forceinline__ float funxform(unsigned u) {
    return (u & 0x80000000u) ? __uint_as_float(u ^ 0x80000000u) : __uint_as_float(~u);
}

__device__ __forceinline__ float sigf(float x) {
    return 1.f / (1.f + __expf(-x));
}
__device__ __forceinline__ float tanhfast(float x) {
    return 1.f - 2.f / (1.f + __expf(2.f * x));
}

// ---------- detect int64 vs int32 edge_index ----------
__global__ void k_detect(const int* __restrict__ idx, int* __restrict__ flag) {
    int v = idx[2 * threadIdx.x + 1];
    unsigned long long b = __ballot(v != 0);
    if (threadIdx.x == 0) flag[0] = (b == 0ULL) ? 1 : 0;
}

// ---------- P[k][h] = sum_c W_edge[k, h*64+c] * att_edge[h, c] ----------
__global__ void k_P(const float* __restrict__ W_edge, const float* __restrict__ att_edge,
                    float* __restrict__ P) {
    int t = threadIdx.x;
    int k = t >> 2, h = t & 3;
    float s = 0.f;
    for (int c = 0; c < 64; ++c) s += W_edge[k * 256 + h * 64 + c] * att_edge[h * 64 + c];
    P[k * 4 + h] = s;
}

// ---------- per-node: xh = x @ W_lin ; a_src, a_dst ----------
__global__ __launch_bounds__(256) void k_node(
    const float* __restrict__ x, const float* __restrict__ W_lin,
    const float* __restrict__ att_s, const float* __restrict__ att_d,
    float* __restrict__ xh, float* __restrict__ asrc, float* __restrict__ adst) {
    int n = blockIdx.x, j = threadIdx.x;
    __shared__ float xr[64];
    if (j < 64) xr[j] = x[n * 64 + j];
    __syncthreads();
    float acc = 0.f;
#pragma unroll
    for (int k = 0; k < 64; ++k) acc += xr[k] * W_lin[k * 256 + j];
    xh[(long)n * 256 + j] = acc;
    float vs = acc * att_s[j], vd = acc * att_d[j];
#pragma unroll
    for (int m = 32; m >= 1; m >>= 1) { vs += __shfl_xor(vs, m); vd += __shfl_xor(vd, m); }
    if ((j & 63) == 0) { int h = j >> 6; asrc[n * 4 + h] = vs; adst[n * 4 + h] = vd; }
}

// ---------- deg + mean_attr accumulation ----------
__global__ void k_edge_accum(const int* __restrict__ idx, const int* __restrict__ flag,
                             const float* __restrict__ ea,
                             float* __restrict__ deg, float* __restrict__ mattr) {
    int e = blockIdx.x * 256 + threadIdx.x;
    if (e >= E_) return;
    int f64 = flag[0];
    int d = edst(idx, e, f64);
    atomicAdd(&deg[d], 1.0f);
    const float4* ep = (const float4*)(ea + (long)e * 16);
    float4 a = ep[0], b = ep[1], c = ep[2], dd = ep[3];
    float* mp = mattr + (long)d * 16;
    atomicAdd(mp + 0, a.x);  atomicAdd(mp + 1, a.y);  atomicAdd(mp + 2, a.z);  atomicAdd(mp + 3, a.w);
    atomicAdd(mp + 4, b.x);  atomicAdd(mp + 5, b.y);  atomicAdd(mp + 6, b.z);  atomicAdd(mp + 7, b.w);
    atomicAdd(mp + 8, c.x);  atomicAdd(mp + 9, c.y);  atomicAdd(mp + 10, c.z); atomicAdd(mp + 11, c.w);
    atomicAdd(mp + 12, dd.x);atomicAdd(mp + 13, dd.y);atomicAdd(mp + 14, dd.z);atomicAdd(mp + 15, dd.w);
}

__global__ void k_meandiv(float* __restrict__ mattr, const float* __restrict__ deg) {
    int i = blockIdx.x * 256 + threadIdx.x;
    if (i >= N_ * 16) return;
    mattr[i] /= fmaxf(deg[i >> 4], 1.0f);
}

// ---------- alpha = leaky_relu(a_src[src]+a_dst[dst]+a_edge) ; segment max ----------
__global__ void k_alpha(const int* __restrict__ idx, const int* __restrict__ flag,
                        const float* __restrict__ ea, const float* __restrict__ mattr,
                        const float* __restrict__ P,
                        const float* __restrict__ asrc, const float* __restrict__ adst,
                        float* __restrict__ alpha, unsigned* __restrict__ amax) {
    int e = blockIdx.x * 256 + threadIdx.x;
    if (e >= E_ + N_) return;
    int f64 = flag[0];
    int s, d;
    const float* ep;
    if (e < E_) { s = esrc(idx, e, f64); d = edst(idx, e, f64); ep = ea + (long)e * 16; }
    else        { s = d = e - E_;        ep = mattr + (long)(e - E_) * 16; }
    float ae[4] = {0.f, 0.f, 0.f, 0.f};
#pragma unroll
    for (int k = 0; k < 16; ++k) {
        float v = ep[k];
#pragma unroll
        for (int h = 0; h < 4; ++h) ae[h] += v * P[k * 4 + h];
    }
#pragma unroll
    for (int h = 0; h < 4; ++h) {
        float al = asrc[s * 4 + h] + adst[d * 4 + h] + ae[h];
        al = (al > 0.f) ? al : NEG_ * al;
        alpha[(long)e * 4 + h] = al;
        atomicMax(&amax[d * 4 + h], fxform(al));
    }
}

// ---------- ex = exp(alpha - amax[dst]) ; segment sum ----------
__global__ void k_ex(const int* __restrict__ idx, const int* __restrict__ flag,
                     float* __restrict__ alpha, const unsigned* __restrict__ amax,
                     float* __restrict__ denom) {
    long i = (long)blockIdx.x * 256 + threadIdx.x;
    if (i >= (long)(E_ + N_) * 4) return;
    int e = (int)(i >> 2), h = (int)(i & 3);
    int f64 = flag[0];
    int d = (e < E_) ? edst(idx, e, f64) : (e - E_);
    float am = funxform(amax[d * 4 + h]);
    if (!isfinite(am)) am = 0.f;
    float ex = __expf(alpha[i] - am);
    alpha[i] = ex;
    atomicAdd(&denom[d * 4 + h], ex);
}

// ---------- weighted scatter: x1[d,c] += sum_h attn * xh[s,h,c] ----------
__global__ __launch_bounds__(256) void k_scatter(
    const int* __restrict__ idx, const int* __restrict__ flag,
    const float* __restrict__ ex, const float* __restrict__ denom,
    const float* __restrict__ xh, float* __restrict__ x1) {
    int e = blockIdx.x * 4 + (threadIdx.x >> 6);
    int c = threadIdx.x & 63;
    if (e >= E_ + N_) return;
    int f64 = flag[0];
    int s, d;
    if (e < E_) { s = esrc(idx, e, f64); d = edst(idx, e, f64); }
    else        { s = d = e - E_; }
    float acc = 0.f;
#pragma unroll
    for (int h = 0; h < 4; ++h) {
        float at = ex[(long)e * 4 + h] / (denom[d * 4 + h] + 1e-16f);
        acc += at * xh[(long)s * 256 + h * 64 + c];
    }
    atomicAdd(&x1[(long)d * 64 + c], acc);
}

// ---------- finalize x1 (mean over heads + bias) and BN stats ----------
__global__ __launch_bounds__(256) void k_x1stats(
    float* __restrict__ x1, const float* __restrict__ bias, float* __restrict__ bnsum) {
    int c = threadIdx.x & 63, r = threadIdx.x >> 6;
    float s = 0.f, s2 = 0.f;
    for (int n = blockIdx.x * 4 + r; n < N_; n += gridDim.x * 4) {
        float v = x1[(long)n * 64 + c] * 0.25f + bias[c];
        x1[(long)n * 64 + c] = v;
        s += v; s2 += v * v;
    }
    __shared__ float red[4][128];
    red[r][c] = s; red[r][64 + c] = s2;
    __syncthreads();
    if (r == 0) {
        float ts = red[0][c] + red[1][c] + red[2][c] + red[3][c];
        float t2 = red[0][64 + c] + red[1][64 + c] + red[2][64 + c] + red[3][64 + c];
        atomicAdd(&bnsum[c], ts);
        atomicAdd(&bnsum[64 + c], t2);
    }
}

__global__ void k_bnfin(const float* __restrict__ bnsum, const float* __restrict__ gamma,
                        const float* __restrict__ beta, float* __restrict__ bnp) {
    int c = threadIdx.x;
    float mu = bnsum[c] / (float)N_;
    float var = bnsum[64 + c] / (float)N_ - mu * mu;
    float sc = gamma[c] * rsqrtf(var + EPS_);
    bnp[c] = sc;
    bnp[64 + c] = beta[c] - mu * sc;
}

// ---------- LSTM: wave handles NB_ nodes, hidden unit per lane ----------
// W4[m][l] = (W_hh[0*64+l][m], W_hh[1*64+l][m], W_hh[2*64+l][m], W_hh[3*64+l][m])
__global__ __launch_bounds__(256) void k_lstm(
    const float* __restrict__ xdyn, const float* __restrict__ W_ih,
    const float* __restrict__ W_hh, const float* __restrict__ b_ih,
    const float* __restrict__ b_hh, float* __restrict__ hlast) {
    __shared__ float4 W4[64 * 64];       // 64 KB
    __shared__ float  hb[4][NB_][64];    // 4 KB
    int t = threadIdx.x;
    int w = t >> 6, l = t & 63;
    // stage W4: 256*64 = 16384 elements = 64 iterations x 256 threads
    for (int it = 0; it < 64; ++it) {
        int id = it * 256 + t;           // W_hh row-major [j=0..255][m=0..63]
        int j = id >> 6, m = id & 63;
        ((float*)W4)[(m * 64 + (j & 63)) * 4 + (j >> 6)] = W_hh[id];
    }
    // biases + W_ih into registers
    float bg[4], wih[8][4];
#pragma unroll
    for (int q = 0; q < 4; ++q) {
        bg[q] = b_ih[q * 64 + l] + b_hh[q * 64 + l];
#pragma unroll
        for (int k = 0; k < 8; ++k) wih[k][q] = W_ih[(q * 64 + l) * 8 + k];
    }
    int nbase = blockIdx.x * (4 * NB_) + w * NB_;
    float h[NB_], c[NB_];
#pragma unroll
    for (int nb = 0; nb < NB_; ++nb) { h[nb] = 0.f; c[nb] = 0.f; hb[w][nb][l] = 0.f; }
    __syncthreads();

    for (int st = 0; st < T_; ++st) {
        float g0[NB_], g1[NB_], g2[NB_], g3[NB_];
#pragma unroll
        for (int nb = 0; nb < NB_; ++nb) {
            g0[nb] = bg[0]; g1[nb] = bg[1]; g2[nb] = bg[2]; g3[nb] = bg[3];
        }
        // x @ W_ih^T  (x loads are wave-uniform, L1-cached)
#pragma unroll
        for (int nb = 0; nb < NB_; ++nb) {
            const float4* xp = (const float4*)(xdyn + ((long)(nbase + nb) * T_ + st) * 8);
            float4 xa = xp[0], xb = xp[1];
            float xv[8] = {xa.x, xa.y, xa.z, xa.w, xb.x, xb.y, xb.z, xb.w};
#pragma unroll
            for (int k = 0; k < 8; ++k) {
                g0[nb] += xv[k] * wih[k][0];
                g1[nb] += xv[k] * wih[k][1];
                g2[nb] += xv[k] * wih[k][2];
                g3[nb] += xv[k] * wih[k][3];
            }
        }
        // h @ W_hh^T : one b128 W read feeds 4 nodes (16 FMA / 16B)
#pragma unroll 4
        for (int m4 = 0; m4 < 16; ++m4) {
            float4 wv0 = W4[(m4 * 4 + 0) * 64 + l];
            float4 wv1 = W4[(m4 * 4 + 1) * 64 + l];
            float4 wv2 = W4[(m4 * 4 + 2) * 64 + l];
            float4 wv3 = W4[(m4 * 4 + 3) * 64 + l];
#pragma unroll
            for (int nb = 0; nb < NB_; ++nb) {
                float4 h4 = *(const float4*)&hb[w][nb][m4 * 4];   // broadcast
                g0[nb] += h4.x * wv0.x + h4.y * wv1.x + h4.z * wv2.x + h4.w * wv3.x;
                g1[nb] += h4.x * wv0.y + h4.y * wv1.y + h4.z * wv2.y + h4.w * wv3.y;
                g2[nb] += h4.x * wv0.z + h4.y * wv1.z + h4.z * wv2.z + h4.w * wv3.z;
                g3[nb] += h4.x * wv0.w + h4.y * wv1.w + h4.z * wv2.w + h4.w * wv3.w;
            }
        }
        __syncthreads();   // all reads of hb done before overwrite
#pragma unroll
        for (int nb = 0; nb < NB_; ++nb) {
            float ig = sigf(g0[nb]);
            float fg = sigf(g1[nb]);
            float gg = tanhfast(g2[nb]);
            float og = sigf(g3[nb]);
            c[nb] = fg * c[nb] + ig * gg;
            h[nb] = og * tanhfast(c[nb]);
            hb[w][nb][l] = h[nb];
        }
        __syncthreads();
    }
#pragma unroll
    for (int nb = 0; nb < NB_; ++nb) hlast[(long)(nbase + nb) * 64 + l] = h[nb];
}

// ---------- head: BN-relu(x1) ++ h_last -> hidden -> out ----------
__global__ __launch_bounds__(256) void k_head(
    const float* __restrict__ x1, const float* __restrict__ hlast,
    const float* __restrict__ bnp, const float* __restrict__ W_hid,
    const float* __restrict__ b_hid, const float* __restrict__ W_out,
    const float* __restrict__ b_out, float* __restrict__ out) {
    int n = blockIdx.x * 256 + threadIdx.x;
    if (n >= N_) return;
    float comb[128];
#pragma unroll
    for (int i = 0; i < 64; ++i)
        comb[i] = fmaxf(x1[(long)n * 64 + i] * bnp[i] + bnp[64 + i], 0.f);
#pragma unroll
    for (int i = 0; i < 64; ++i) comb[64 + i] = hlast[(long)n * 64 + i];
    float o = b_out[0];
    for (int j = 0; j < 32; ++j) {
        float a = b_hid[j];
#pragma unroll
        for (int i = 0; i < 128; ++i) a += comb[i] * W_hid[i * 32 + j];
        o += fmaxf(a, 0.f) * W_out[j];
    }
    out[n] = o;
}

extern "C" void kernel_launch(void* const* d_in, const int* in_sizes, int n_in,
                              void* d_out, int out_size, void* d_ws, size_t ws_size,
                              hipStream_t stream) {
    const float* x_node   = (const float*)d_in[0];
    const float* ea       = (const float*)d_in[1];
    const float* xdyn     = (const float*)d_in[2];
    const int*   eidx     = (const int*)d_in[3];
    const float* W_lin    = (const float*)d_in[4];
    const float* W_edge   = (const float*)d_in[5];
    const float* att_src  = (const float*)d_in[6];
    const float* att_dst  = (const float*)d_in[7];
    const float* att_edge = (const float*)d_in[8];
    const float* gat_bias = (const float*)d_in[9];
    const float* bn_gamma = (const float*)d_in[10];
    const float* bn_beta  = (const float*)d_in[11];
    const float* W_ih     = (const float*)d_in[12];
    const float* W_hh     = (const float*)d_in[13];
    const float* b_ih     = (const float*)d_in[14];
    const float* b_hh     = (const float*)d_in[15];
    const float* W_hid    = (const float*)d_in[16];
    const float* b_hid    = (const float*)d_in[17];
    const float* W_out    = (const float*)d_in[18];
    const float* b_out    = (const float*)d_in[19];
    float* out = (float*)d_out;

    char* ws = (char*)d_ws;
    size_t off = 0;
    auto alloc = [&](size_t bytes) -> void* {
        void* p = ws + off;
        off = (off + bytes + 255) & ~(size_t)255;
        return p;
    };
    int*      flag  = (int*)alloc(4);
    float*    P     = (float*)alloc(64 * 4);
    float*    bnp   = (float*)alloc(128 * 4);
    char*     zs    = ws + off;                       // ---- zero region start
    float*    bnsum = (float*)alloc(128 * 4);
    float*    deg   = (float*)alloc((size_t)N_ * 4);
    float*    mattr = (float*)alloc((size_t)N_ * 16 * 4);
    unsigned* amax  = (unsigned*)alloc((size_t)N_ * 4 * 4);
    float*    denom = (float*)alloc((size_t)N_ * 4 * 4);
    float*    x1    = (float*)alloc((size_t)N_ * 64 * 4);
    size_t zbytes = (size_t)((ws + off) - zs);        // ---- zero region end
    float*    alpha = (float*)alloc((size_t)(E_ + N_) * 4 * 4);
    float*    xh    = (float*)alloc((size_t)N_ * 256 * 4);
    float*    asrc  = (float*)alloc((size_t)N_ * 4 * 4);
    float*    adst  = (float*)alloc((size_t)N_ * 4 * 4);
    float*    hlast = (float*)alloc((size_t)N_ * 64 * 4);
    (void)ws_size; (void)in_sizes; (void)n_in; (void)out_size;

    hipMemsetAsync(zs, 0, zbytes, stream);
    k_detect<<<1, 64, 0, stream>>>(eidx, flag);
    k_P<<<1, 64, 0, stream>>>(W_edge, att_edge, P);
    k_node<<<N_, 256, 0, stream>>>(x_node, W_lin, att_src, att_dst, xh, asrc, adst);
    k_edge_accum<<<(E_ + 255) / 256, 256, 0, stream>>>(eidx, flag, ea, deg, mattr);
    k_meandiv<<<(N_ * 16 + 255) / 256, 256, 0, stream>>>(mattr, deg);
    k_alpha<<<(E_ + N_ + 255) / 256, 256, 0, stream>>>(eidx, flag, ea, mattr, P, asrc, adst, alpha, amax);
    k_ex<<<(int)(((long)(E_ + N_) * 4 + 255) / 256), 256, 0, stream>>>(eidx, flag, alpha, amax, denom);
    k_scatter<<<(E_ + N_ + 3) / 4, 256, 0, stream>>>(eidx, flag, alpha, denom, xh, x1);
    k_x1stats<<<128, 256, 0, stream>>>(x1, gat_bias, bnsum);
    k_bnfin<<<1, 64, 0, stream>>>(bnsum, bn_gamma, bn_beta, bnp);
    k_lstm<<<N_ / (4 * NB_), 256, 0, stream>>>(xdyn, W_ih, W_hh, b_ih, b_hh, hlast);
    k_head<<<(N_ + 255) / 256, 256, 0, stream>>>(x1, hlast, bnp, W_hid, b_hid, W_out, b_out, out);
}

// Round 4
// 860.315 us; speedup vs baseline: 2.2405x; 1.3921x over previous
//
#include <hip/hip_runtime.h>
#include <hip/hip_bf16.h>

constexpr int N_  = 20000;
constexpr int E_  = 320000;
constexpr int T_  = 24;
constexpr float NEG_ = 0.2f;
constexpr float EPS_ = 1e-5f;

typedef __attribute__((ext_vector_type(8)))  short short8v;
typedef __attribute__((ext_vector_type(16))) float f32x16;

// ---------- edge_index accessors (int32 vs int64 runtime-detected) ----------
__device__ __forceinline__ int esrc(const int* __restrict__ p, int e, int f64) {
    return f64 ? p[4 * e] : p[2 * e];
}
__device__ __forceinline__ int edst(const int* __restrict__ p, int e, int f64) {
    return f64 ? p[4 * e + 2] : p[2 * e + 1];
}

// monotone float<->uint transform for atomicMax on floats
__device__ __forceinline__ unsigned fxform(float f) {
    unsigned u = __float_as_uint(f);
    return (u & 0x80000000u) ? ~u : (u | 0x80000000u);
}
__device__ __forceinline__ float funxform(unsigned u) {
    return (u & 0x80000000u) ? __uint_as_float(u ^ 0x80000000u) : __uint_as_float(~u);
}

__device__ __forceinline__ float sigf(float x) {
    return 1.f / (1.f + __expf(-x));
}
__device__ __forceinline__ float tanhfast(float x) {
    return 1.f - 2.f / (1.f + __expf(2.f * x));
}

// f32 -> bf16 with round-to-nearest-even
__device__ __forceinline__ short f2bf(float f) {
    union { float f; unsigned u; } v; v.f = f;
    unsigned r = v.u + 0x7FFFu + ((v.u >> 16) & 1u);
    return (short)(r >> 16);
}

// ---------- detect int64 vs int32 edge_index ----------
__global__ void k_detect(const int* __restrict__ idx, int* __restrict__ flag) {
    int v = idx[2 * threadIdx.x + 1];
    unsigned long long b = __ballot(v != 0);
    if (threadIdx.x == 0) flag[0] = (b == 0ULL) ? 1 : 0;
}

// ---------- P[k][h] = sum_c W_edge[k, h*64+c] * att_edge[h, c] ----------
__global__ void k_P(const float* __restrict__ W_edge, const float* __restrict__ att_edge,
                    float* __restrict__ P) {
    int t = threadIdx.x;
    int k = t >> 2, h = t & 3;
    float s = 0.f;
    for (int c = 0; c < 64; ++c) s += W_edge[k * 256 + h * 64 + c] * att_edge[h * 64 + c];
    P[k * 4 + h] = s;
}

// ---------- per-node: xh = x @ W_lin ; a_src, a_dst ----------
__global__ __launch_bounds__(256) void k_node(
    const float* __restrict__ x, const float* __restrict__ W_lin,
    const float* __restrict__ att_s, const float* __restrict__ att_d,
    float* __restrict__ xh, float* __restrict__ asrc, float* __restrict__ adst) {
    int n = blockIdx.x, j = threadIdx.x;
    __shared__ float xr[64];
    if (j < 64) xr[j] = x[n * 64 + j];
    __syncthreads();
    float acc = 0.f;
#pragma unroll
    for (int k = 0; k < 64; ++k) acc += xr[k] * W_lin[k * 256 + j];
    xh[(long)n * 256 + j] = acc;
    float vs = acc * att_s[j], vd = acc * att_d[j];
#pragma unroll
    for (int m = 32; m >= 1; m >>= 1) { vs += __shfl_xor(vs, m); vd += __shfl_xor(vd, m); }
    if ((j & 63) == 0) { int h = j >> 6; asrc[n * 4 + h] = vs; adst[n * 4 + h] = vd; }
}

// ---------- deg + mean_attr accumulation ----------
__global__ void k_edge_accum(const int* __restrict__ idx, const int* __restrict__ flag,
                             const float* __restrict__ ea,
                             float* __restrict__ deg, float* __restrict__ mattr) {
    int e = blockIdx.x * 256 + threadIdx.x;
    if (e >= E_) return;
    int f64 = flag[0];
    int d = edst(idx, e, f64);
    atomicAdd(&deg[d], 1.0f);
    const float4* ep = (const float4*)(ea + (long)e * 16);
    float4 a = ep[0], b = ep[1], c = ep[2], dd = ep[3];
    float* mp = mattr + (long)d * 16;
    atomicAdd(mp + 0, a.x);  atomicAdd(mp + 1, a.y);  atomicAdd(mp + 2, a.z);  atomicAdd(mp + 3, a.w);
    atomicAdd(mp + 4, b.x);  atomicAdd(mp + 5, b.y);  atomicAdd(mp + 6, b.z);  atomicAdd(mp + 7, b.w);
    atomicAdd(mp + 8, c.x);  atomicAdd(mp + 9, c.y);  atomicAdd(mp + 10, c.z); atomicAdd(mp + 11, c.w);
    atomicAdd(mp + 12, dd.x);atomicAdd(mp + 13, dd.y);atomicAdd(mp + 14, dd.z);atomicAdd(mp + 15, dd.w);
}

__global__ void k_meandiv(float* __restrict__ mattr, const float* __restrict__ deg) {
    int i = blockIdx.x * 256 + threadIdx.x;
    if (i >= N_ * 16) return;
    mattr[i] /= fmaxf(deg[i >> 4], 1.0f);
}

// ---------- alpha = leaky_relu(a_src[src]+a_dst[dst]+a_edge) ; segment max ----------
__global__ void k_alpha(const int* __restrict__ idx, const int* __restrict__ flag,
                        const float* __restrict__ ea, const float* __restrict__ mattr,
                        const float* __restrict__ P,
                        const float* __restrict__ asrc, const float* __restrict__ adst,
                        float* __restrict__ alpha, unsigned* __restrict__ amax) {
    int e = blockIdx.x * 256 + threadIdx.x;
    if (e >= E_ + N_) return;
    int f64 = flag[0];
    int s, d;
    const float* ep;
    if (e < E_) { s = esrc(idx, e, f64); d = edst(idx, e, f64); ep = ea + (long)e * 16; }
    else        { s = d = e - E_;        ep = mattr + (long)(e - E_) * 16; }
    float ae[4] = {0.f, 0.f, 0.f, 0.f};
#pragma unroll
    for (int k = 0; k < 16; ++k) {
        float v = ep[k];
#pragma unroll
        for (int h = 0; h < 4; ++h) ae[h] += v * P[k * 4 + h];
    }
#pragma unroll
    for (int h = 0; h < 4; ++h) {
        float al = asrc[s * 4 + h] + adst[d * 4 + h] + ae[h];
        al = (al > 0.f) ? al : NEG_ * al;
        alpha[(long)e * 4 + h] = al;
        atomicMax(&amax[d * 4 + h], fxform(al));
    }
}

// ---------- ex = exp(alpha - amax[dst]) ; segment sum ----------
__global__ void k_ex(const int* __restrict__ idx, const int* __restrict__ flag,
                     float* __restrict__ alpha, const unsigned* __restrict__ amax,
                     float* __restrict__ denom) {
    long i = (long)blockIdx.x * 256 + threadIdx.x;
    if (i >= (long)(E_ + N_) * 4) return;
    int e = (int)(i >> 2), h = (int)(i & 3);
    int f64 = flag[0];
    int d = (e < E_) ? edst(idx, e, f64) : (e - E_);
    float am = funxform(amax[d * 4 + h]);
    if (!isfinite(am)) am = 0.f;
    float ex = __expf(alpha[i] - am);
    alpha[i] = ex;
    atomicAdd(&denom[d * 4 + h], ex);
}

// ---------- weighted scatter: x1[d,c] += sum_h attn * xh[s,h,c] ----------
__global__ __launch_bounds__(256) void k_scatter(
    const int* __restrict__ idx, const int* __restrict__ flag,
    const float* __restrict__ ex, const float* __restrict__ denom,
    const float* __restrict__ xh, float* __restrict__ x1) {
    int e = blockIdx.x * 4 + (threadIdx.x >> 6);
    int c = threadIdx.x & 63;
    if (e >= E_ + N_) return;
    int f64 = flag[0];
    int s, d;
    if (e < E_) { s = esrc(idx, e, f64); d = edst(idx, e, f64); }
    else        { s = d = e - E_; }
    float acc = 0.f;
#pragma unroll
    for (int h = 0; h < 4; ++h) {
        float at = ex[(long)e * 4 + h] / (denom[d * 4 + h] + 1e-16f);
        acc += at * xh[(long)s * 256 + h * 64 + c];
    }
    atomicAdd(&x1[(long)d * 64 + c], acc);
}

// ---------- finalize x1 (mean over heads + bias) and BN stats ----------
__global__ __launch_bounds__(256) void k_x1stats(
    float* __restrict__ x1, const float* __restrict__ bias, float* __restrict__ bnsum) {
    int c = threadIdx.x & 63, r = threadIdx.x >> 6;
    float s = 0.f, s2 = 0.f;
    for (int n = blockIdx.x * 4 + r; n < N_; n += gridDim.x * 4) {
        float v = x1[(long)n * 64 + c] * 0.25f + bias[c];
        x1[(long)n * 64 + c] = v;
        s += v; s2 += v * v;
    }
    __shared__ float red[4][128];
    red[r][c] = s; red[r][64 + c] = s2;
    __syncthreads();
    if (r == 0) {
        float ts = red[0][c] + red[1][c] + red[2][c] + red[3][c];
        float t2 = red[0][64 + c] + red[1][64 + c] + red[2][64 + c] + red[3][64 + c];
        atomicAdd(&bnsum[c], ts);
        atomicAdd(&bnsum[64 + c], t2);
    }
}

__global__ void k_bnfin(const float* __restrict__ bnsum, const float* __restrict__ gamma,
                        const float* __restrict__ beta, float* __restrict__ bnp) {
    int c = threadIdx.x;
    float mu = bnsum[c] / (float)N_;
    float var = bnsum[64 + c] / (float)N_ - mu * mu;
    float sc = gamma[c] * rsqrtf(var + EPS_);
    bnp[c] = sc;
    bnp[64 + c] = beta[c] - mu * sc;
}

// ---------- LSTM via MFMA: 1 wave per 32 nodes ----------
// gates[32 x 256] = [h(64) | x(8),1,pad] @ [W_hh^T ; W_ih^T ; bias] per step.
// 32x32x16 bf16 MFMA. Assumed frag k-map km(g,e)=8g+e used identically on A
// and B sides (any consistent bijection cancels). C/D layout (HW-verified):
// col = lane&31, row = (r&3) + 8*(r>>2) + 4*(lane>>5).
__global__ __launch_bounds__(64, 1) void k_lstm_mfma(
    const float* __restrict__ xdyn, const float* __restrict__ W_ih,
    const float* __restrict__ W_hh, const float* __restrict__ b_ih,
    const float* __restrict__ b_hh, float* __restrict__ hlast) {
    __shared__ short Hl[32 * 64];        // h as bf16, [m][j], XOR-swizzled, 4 KB
    char* Hb = (char*)Hl;
    const int l = threadIdx.x;
    const int lm = l & 31;               // row (A) / col (B/C) lane index
    const int g  = l >> 5;               // k-group
    const int nbase = blockIdx.x * 32;

    // ---- stage W_hh fragments into registers: Bh[t8][ks] ----
    // B[k][j] = W_hh[j][k]; slot (g,e) of k-slice ks -> k = 16ks + 8g + e
    short8v Bh[8][4];
#pragma unroll
    for (int t8 = 0; t8 < 8; ++t8) {
#pragma unroll
        for (int ks = 0; ks < 4; ++ks) {
            int j = 32 * t8 + lm;
            const float* wp = W_hh + j * 64 + 16 * ks + 8 * g;
            float4 wa = *(const float4*)wp;
            float4 wb = *(const float4*)(wp + 4);
            short8v f;
            f[0] = f2bf(wa.x); f[1] = f2bf(wa.y); f[2] = f2bf(wa.z); f[3] = f2bf(wa.w);
            f[4] = f2bf(wb.x); f[5] = f2bf(wb.y); f[6] = f2bf(wb.z); f[7] = f2bf(wb.w);
            Bh[t8][ks] = f;
        }
    }
    // ---- stage [W_ih^T ; bias ; 0] fragments: B2[t8] (K=16 slice) ----
    short8v B2[8];
#pragma unroll
    for (int t8 = 0; t8 < 8; ++t8) {
        int j = 32 * t8 + lm;
        short8v f;
        if (g == 0) {                    // k = 0..7 -> W_ih[j][k]
            const float* wp = W_ih + j * 8;
            float4 wa = *(const float4*)wp;
            float4 wb = *(const float4*)(wp + 4);
            f[0] = f2bf(wa.x); f[1] = f2bf(wa.y); f[2] = f2bf(wa.z); f[3] = f2bf(wa.w);
            f[4] = f2bf(wb.x); f[5] = f2bf(wb.y); f[6] = f2bf(wb.z); f[7] = f2bf(wb.w);
        } else {                         // k = 8 -> bias row; 9..15 -> 0
#pragma unroll
            for (int e = 0; e < 8; ++e) f[e] = 0;
            f[0] = f2bf(b_ih[j] + b_hh[j]);
        }
        B2[t8] = f;
    }
    // constant x-A fragment for lanes 32-63: k=8 -> 1.0, rest 0
    short8v xAc;
#pragma unroll
    for (int e = 0; e < 8; ++e) xAc[e] = 0;
    xAc[0] = (short)0x3F80;

    f32x16 zc;
#pragma unroll
    for (int e = 0; e < 16; ++e) zc[e] = 0.f;

    // zero H (h0 = 0)
#pragma unroll
    for (int i = l; i < 256; i += 64) ((short8v*)Hl)[i] = xAc * (short)0;  // zero vec
    {
        short8v zv;
#pragma unroll
        for (int e = 0; e < 8; ++e) zv[e] = 0;
#pragma unroll
        for (int i = l; i < 256; i += 64) ((short8v*)Hl)[i] = zv;
    }
    float cst[2][16];
#pragma unroll
    for (int jt = 0; jt < 2; ++jt)
#pragma unroll
        for (int r = 0; r < 16; ++r) cst[jt][r] = 0.f;

    __syncthreads();

    const float* xbase = xdyn + (long)(nbase + lm) * T_ * 8;
    float4 xp0, xp1;
    if (g == 0) { xp0 = *(const float4*)xbase; xp1 = *(const float4*)(xbase + 4); }

    for (int t = 0; t < T_; ++t) {
        // build x A-fragment; prefetch next step's x
        short8v xA;
        if (g == 0) {
            xA[0] = f2bf(xp0.x); xA[1] = f2bf(xp0.y); xA[2] = f2bf(xp0.z); xA[3] = f2bf(xp0.w);
            xA[4] = f2bf(xp1.x); xA[5] = f2bf(xp1.y); xA[6] = f2bf(xp1.z); xA[7] = f2bf(xp1.w);
            if (t < T_ - 1) {
                xp0 = *(const float4*)(xbase + (t + 1) * 8);
                xp1 = *(const float4*)(xbase + (t + 1) * 8 + 4);
            }
        } else xA = xAc;

        // gates init: x-projection + bias (zc as C-in, no per-step zeroing)
        f32x16 acc[8];
#pragma unroll
        for (int t8 = 0; t8 < 8; ++t8)
            acc[t8] = __builtin_amdgcn_mfma_f32_32x32x16_bf16(xA, B2[t8], zc, 0, 0, 0);

        // h A-fragments from LDS (swizzled)
        short8v hA[4];
#pragma unroll
        for (int ks = 0; ks < 4; ++ks) {
            int raddr = (lm * 128 + 32 * ks + 16 * g) ^ ((lm & 7) << 4);
            hA[ks] = *(const short8v*)(Hb + raddr);
        }
#pragma unroll
        for (int ks = 0; ks < 4; ++ks)
#pragma unroll
            for (int t8 = 0; t8 < 8; ++t8)
                acc[t8] = __builtin_amdgcn_mfma_f32_32x32x16_bf16(hA[ks], Bh[t8][ks], acc[t8], 0, 0, 0);

        __syncthreads();   // A-reads done before h overwrite (1 wave: cheap)

        // elementwise gates -> c,h ; write h back to LDS as bf16
#pragma unroll
        for (int jt = 0; jt < 2; ++jt) {
#pragma unroll
            for (int r = 0; r < 16; ++r) {
                float iv = acc[jt][r];
                float fv = acc[2 + jt][r];
                float gv = acc[4 + jt][r];
                float ov = acc[6 + jt][r];
                float si = sigf(iv), sf = sigf(fv), tg = tanhfast(gv), so = sigf(ov);
                float cn = sf * cst[jt][r] + si * tg;
                cst[jt][r] = cn;
                float hn = so * tanhfast(cn);
                int mrow = (r & 3) + 8 * (r >> 2) + 4 * g;
                int j = 32 * jt + lm;
                int waddr = (mrow * 128 + j * 2) ^ ((mrow & 7) << 4);
                *(short*)(Hb + waddr) = f2bf(hn);
                if (t == T_ - 1) hlast[(long)(nbase + mrow) * 64 + j] = hn;
            }
        }
        __syncthreads();
    }
}

// ---------- head: BN-relu(x1) ++ h_last -> hidden -> out ----------
__global__ __launch_bounds__(256) void k_head(
    const float* __restrict__ x1, const float* __restrict__ hlast,
    const float* __restrict__ bnp, const float* __restrict__ W_hid,
    const float* __restrict__ b_hid, const float* __restrict__ W_out,
    const float* __restrict__ b_out, float* __restrict__ out) {
    int n = blockIdx.x * 256 + threadIdx.x;
    if (n >= N_) return;
    float comb[128];
#pragma unroll
    for (int i = 0; i < 64; ++i)
        comb[i] = fmaxf(x1[(long)n * 64 + i] * bnp[i] + bnp[64 + i], 0.f);
#pragma unroll
    for (int i = 0; i < 64; ++i) comb[64 + i] = hlast[(long)n * 64 + i];
    float o = b_out[0];
    for (int j = 0; j < 32; ++j) {
        float a = b_hid[j];
#pragma unroll
        for (int i = 0; i < 128; ++i) a += comb[i] * W_hid[i * 32 + j];
        o += fmaxf(a, 0.f) * W_out[j];
    }
    out[n] = o;
}

extern "C" void kernel_launch(void* const* d_in, const int* in_sizes, int n_in,
                              void* d_out, int out_size, void* d_ws, size_t ws_size,
                              hipStream_t stream) {
    const float* x_node   = (const float*)d_in[0];
    const float* ea       = (const float*)d_in[1];
    const float* xdyn     = (const float*)d_in[2];
    const int*   eidx     = (const int*)d_in[3];
    const float* W_lin    = (const float*)d_in[4];
    const float* W_edge   = (const float*)d_in[5];
    const float* att_src  = (const float*)d_in[6];
    const float* att_dst  = (const float*)d_in[7];
    const float* att_edge = (const float*)d_in[8];
    const float* gat_bias = (const float*)d_in[9];
    const float* bn_gamma = (const float*)d_in[10];
    const float* bn_beta  = (const float*)d_in[11];
    const float* W_ih     = (const float*)d_in[12];
    const float* W_hh     = (const float*)d_in[13];
    const float* b_ih     = (const float*)d_in[14];
    const float* b_hh     = (const float*)d_in[15];
    const float* W_hid    = (const float*)d_in[16];
    const float* b_hid    = (const float*)d_in[17];
    const float* W_out    = (const float*)d_in[18];
    const float* b_out    = (const float*)d_in[19];
    float* out = (float*)d_out;

    char* ws = (char*)d_ws;
    size_t off = 0;
    auto alloc = [&](size_t bytes) -> void* {
        void* p = ws + off;
        off = (off + bytes + 255) & ~(size_t)255;
        return p;
    };
    int*      flag  = (int*)alloc(4);
    float*    P     = (float*)alloc(64 * 4);
    float*    bnp   = (float*)alloc(128 * 4);
    char*     zs    = ws + off;                       // ---- zero region start
    float*    bnsum = (float*)alloc(128 * 4);
    float*    deg   = (float*)alloc((size_t)N_ * 4);
    float*    mattr = (float*)alloc((size_t)N_ * 16 * 4);
    unsigned* amax  = (unsigned*)alloc((size_t)N_ * 4 * 4);
    float*    denom = (float*)alloc((size_t)N_ * 4 * 4);
    float*    x1    = (float*)alloc((size_t)N_ * 64 * 4);
    size_t zbytes = (size_t)((ws + off) - zs);        // ---- zero region end
    float*    alpha = (float*)alloc((size_t)(E_ + N_) * 4 * 4);
    float*    xh    = (float*)alloc((size_t)N_ * 256 * 4);
    float*    asrc  = (float*)alloc((size_t)N_ * 4 * 4);
    float*    adst  = (float*)alloc((size_t)N_ * 4 * 4);
    float*    hlast = (float*)alloc((size_t)N_ * 64 * 4);
    (void)ws_size; (void)in_sizes; (void)n_in; (void)out_size;

    hipMemsetAsync(zs, 0, zbytes, stream);
    k_detect<<<1, 64, 0, stream>>>(eidx, flag);
    k_P<<<1, 64, 0, stream>>>(W_edge, att_edge, P);
    k_node<<<N_, 256, 0, stream>>>(x_node, W_lin, att_src, att_dst, xh, asrc, adst);
    k_edge_accum<<<(E_ + 255) / 256, 256, 0, stream>>>(eidx, flag, ea, deg, mattr);
    k_meandiv<<<(N_ * 16 + 255) / 256, 256, 0, stream>>>(mattr, deg);
    k_alpha<<<(E_ + N_ + 255) / 256, 256, 0, stream>>>(eidx, flag, ea, mattr, P, asrc, adst, alpha, amax);
    k_ex<<<(int)(((long)(E_ + N_) * 4 + 255) / 256), 256, 0, stream>>>(eidx, flag, alpha, amax, denom);
    k_scatter<<<(E_ + N_ + 3) / 4, 256, 0, stream>>>(eidx, flag, alpha, denom, xh, x1);
    k_x1stats<<<128, 256, 0, stream>>>(x1, gat_bias, bnsum);
    k_bnfin<<<1, 64, 0, stream>>>(bnsum, bn_gamma, bn_beta, bnp);
    k_lstm_mfma<<<N_ / 32, 64, 0, stream>>>(xdyn, W_ih, W_hh, b_ih, b_hh, hlast);
    k_head<<<(N_ + 255) / 256, 256, 0, stream>>>(x1, hlast, bnp, W_hid, b_hid, W_out, b_out, out);
}

// Round 5
// 536.309 us; speedup vs baseline: 3.5940x; 1.6041x over previous
//
#include <hip/hip_runtime.h>
#include <hip/hip_bf16.h>

constexpr int N_  = 20000;
constexpr int E_  = 320000;
constexpr int T_  = 24;
constexpr float NEG_ = 0.2f;
constexpr float EPS_ = 1e-5f;
constexpr int MAXD_ = 128;              // LDS edge-cache per node (fallback past this)

typedef __attribute__((ext_vector_type(8)))  short short8v;
typedef __attribute__((ext_vector_type(16))) float f32x16;

// ---------- edge_index accessors (int32 vs int64 runtime-detected) ----------
__device__ __forceinline__ int esrc(const int* __restrict__ p, int e, int f64) {
    return f64 ? p[4 * e] : p[2 * e];
}
__device__ __forceinline__ int edst(const int* __restrict__ p, int e, int f64) {
    return f64 ? p[4 * e + 2] : p[2 * e + 1];
}

__device__ __forceinline__ float sigf(float x) {
    return 1.f / (1.f + __expf(-x));
}
__device__ __forceinline__ float tanhfast(float x) {
    return 1.f - 2.f / (1.f + __expf(2.f * x));
}

// f32 -> bf16 round-to-nearest-even
__device__ __forceinline__ short f2bf(float f) {
    union { float f; unsigned u; } v; v.f = f;
    unsigned r = v.u + 0x7FFFu + ((v.u >> 16) & 1u);
    return (short)(r >> 16);
}

// ---------- detect int64 vs int32 edge_index ----------
__global__ void k_detect(const int* __restrict__ idx, int* __restrict__ flag) {
    int v = idx[2 * threadIdx.x + 1];
    unsigned long long b = __ballot(v != 0);
    if (threadIdx.x == 0) flag[0] = (b == 0ULL) ? 1 : 0;
}

// ---------- P[k][h] = sum_c W_edge[k, h*64+c] * att_edge[h, c] ----------
__global__ void k_P(const float* __restrict__ W_edge, const float* __restrict__ att_edge,
                    float* __restrict__ P) {
    int t = threadIdx.x;
    int k = t >> 2, h = t & 3;
    float s = 0.f;
    for (int c = 0; c < 64; ++c) s += W_edge[k * 256 + h * 64 + c] * att_edge[h * 64 + c];
    P[k * 4 + h] = s;
}

// ---------- per-node: xh = x @ W_lin ; a_src, a_dst ----------
__global__ __launch_bounds__(256) void k_node(
    const float* __restrict__ x, const float* __restrict__ W_lin,
    const float* __restrict__ att_s, const float* __restrict__ att_d,
    float* __restrict__ xh, float* __restrict__ asrc, float* __restrict__ adst) {
    int n = blockIdx.x, j = threadIdx.x;
    __shared__ float xr[64];
    if (j < 64) xr[j] = x[n * 64 + j];
    __syncthreads();
    float acc = 0.f;
#pragma unroll
    for (int k = 0; k < 64; ++k) acc += xr[k] * W_lin[k * 256 + j];
    xh[(long)n * 256 + j] = acc;
    float vs = acc * att_s[j], vd = acc * att_d[j];
#pragma unroll
    for (int m = 32; m >= 1; m >>= 1) { vs += __shfl_xor(vs, m); vd += __shfl_xor(vd, m); }
    if ((j & 63) == 0) { int h = j >> 6; asrc[n * 4 + h] = vs; adst[n * 4 + h] = vd; }
}

// ---------- E1: ae[e][h] = P^T . ea[e] ; deg count ----------
__global__ __launch_bounds__(256) void k_e1(
    const int* __restrict__ idx, const int* __restrict__ flag,
    const float* __restrict__ ea, const float* __restrict__ P,
    float4* __restrict__ aebuf, int* __restrict__ degi) {
    __shared__ float Ps[256];
    int t = threadIdx.x;
    Ps[t] = P[t];
    __syncthreads();
    int e = blockIdx.x * 256 + t;
    if (e >= E_) return;
    int f64 = flag[0];
    int d = edst(idx, e, f64);
    const float* ep = ea + (long)e * 16;
    float ae[4] = {0.f, 0.f, 0.f, 0.f};
#pragma unroll
    for (int k = 0; k < 16; ++k) {
        float v = ep[k];
#pragma unroll
        for (int h = 0; h < 4; ++h) ae[h] += v * Ps[k * 4 + h];
    }
    aebuf[e] = make_float4(ae[0], ae[1], ae[2], ae[3]);
    atomicAdd(&degi[d], 1);
}

// ---------- exclusive prefix scan of degi (single block) ----------
__global__ __launch_bounds__(256) void k_scan(const int* __restrict__ degi,
                                              int* __restrict__ offs) {
    __shared__ int part[256];
    int t = threadIdx.x;
    int base = t * 80;
    int s = 0;
    for (int i = 0; i < 80; ++i) { int ix = base + i; if (ix < N_) s += degi[ix]; }
    part[t] = s;
    __syncthreads();
    for (int d = 1; d < 256; d <<= 1) {
        int v = (t >= d) ? part[t - d] : 0;
        __syncthreads();
        part[t] += v;
        __syncthreads();
    }
    int run = (t > 0) ? part[t - 1] : 0;
    for (int i = 0; i < 80; ++i) {
        int ix = base + i;
        if (ix < N_) { offs[ix] = run; run += degi[ix]; }
    }
}

// ---------- E2: counting-sort edges into CSR (slot -> (edge, src)) ----------
__global__ __launch_bounds__(256) void k_e2(
    const int* __restrict__ idx, const int* __restrict__ flag,
    const int* __restrict__ offs, int* __restrict__ cursor,
    int2* __restrict__ csr) {
    int e = blockIdx.x * 256 + threadIdx.x;
    if (e >= E_) return;
    int f64 = flag[0];
    int d = edst(idx, e, f64);
    int s = esrc(idx, e, f64);
    int pos = atomicAdd(&cursor[d], 1);
    csr[offs[d] + pos] = make_int2(e, s);
}

// ---------- N2: per-dst softmax + gather (no atomics), fused x1 epilogue ----------
__global__ __launch_bounds__(256) void k_n2(
    const int* __restrict__ offs, const int* __restrict__ degi,
    const int2* __restrict__ csr, const float4* __restrict__ aebuf,
    const float4* __restrict__ asrc4, const float4* __restrict__ adst4,
    const float* __restrict__ xh, const float* __restrict__ gat_bias,
    float* __restrict__ x1) {
    __shared__ int   sS[4][MAXD_];
    __shared__ float4 sEx[4][MAXD_];
    int t = threadIdx.x, w = t >> 6, lane = t & 63;
    int n = blockIdx.x * 4 + w;
    if (n >= N_) return;
    int deg = degi[n], off = offs[n];
    float4 ad = adst4[n];

    // phase 1 (lane-parallel): per-edge ex, cache (s, ex); partial aesum/denom
    float4 aesum = make_float4(0, 0, 0, 0), den = make_float4(0, 0, 0, 0);
    for (int base = 0; base < deg; base += 64) {
        int i = base + lane;
        if (i < deg) {
            int2 pr = csr[off + i];
            float4 ae = aebuf[pr.x];
            float4 as = asrc4[pr.y];
            float a0 = as.x + ad.x + ae.x; a0 = a0 > 0.f ? a0 : NEG_ * a0;
            float a1 = as.y + ad.y + ae.y; a1 = a1 > 0.f ? a1 : NEG_ * a1;
            float a2 = as.z + ad.z + ae.z; a2 = a2 > 0.f ? a2 : NEG_ * a2;
            float a3 = as.w + ad.w + ae.w; a3 = a3 > 0.f ? a3 : NEG_ * a3;
            float4 ex = make_float4(__expf(a0), __expf(a1), __expf(a2), __expf(a3));
            aesum.x += ae.x; aesum.y += ae.y; aesum.z += ae.z; aesum.w += ae.w;
            den.x += ex.x; den.y += ex.y; den.z += ex.z; den.w += ex.w;
            if (i < MAXD_) { sS[w][i] = pr.y; sEx[w][i] = ex; }
        }
    }
#pragma unroll
    for (int m = 32; m >= 1; m >>= 1) {
        aesum.x += __shfl_xor(aesum.x, m); aesum.y += __shfl_xor(aesum.y, m);
        aesum.z += __shfl_xor(aesum.z, m); aesum.w += __shfl_xor(aesum.w, m);
        den.x += __shfl_xor(den.x, m); den.y += __shfl_xor(den.y, m);
        den.z += __shfl_xor(den.z, m); den.w += __shfl_xor(den.w, m);
    }
    // self-loop: ae_self = aesum/max(deg,1)
    float dv = fmaxf((float)deg, 1.f);
    float4 as = asrc4[n];
    float a0 = as.x + ad.x + aesum.x / dv; a0 = a0 > 0.f ? a0 : NEG_ * a0;
    float a1 = as.y + ad.y + aesum.y / dv; a1 = a1 > 0.f ? a1 : NEG_ * a1;
    float a2 = as.z + ad.z + aesum.z / dv; a2 = a2 > 0.f ? a2 : NEG_ * a2;
    float a3 = as.w + ad.w + aesum.w / dv; a3 = a3 > 0.f ? a3 : NEG_ * a3;
    float4 exs = make_float4(__expf(a0), __expf(a1), __expf(a2), __expf(a3));
    den.x += exs.x; den.y += exs.y; den.z += exs.z; den.w += exs.w;
    float i0 = 1.f / (den.x + 1e-16f), i1 = 1.f / (den.y + 1e-16f);
    float i2 = 1.f / (den.z + 1e-16f), i3 = 1.f / (den.w + 1e-16f);
    __syncthreads();   // sS/sEx visible wave-internally anyway; cheap

    // phase 2 (uniform loop, coalesced xh gather): acc = sum_e sum_h attn*xh
    float acc = 0.f;
    for (int i = 0; i < deg; ++i) {
        int s; float4 ex;
        if (i < MAXD_) { s = sS[w][i]; ex = sEx[w][i]; }
        else {
            int2 pr = csr[off + i];
            s = pr.y;
            float4 ae = aebuf[pr.x];
            float4 a5 = asrc4[s];
            float b0 = a5.x + ad.x + ae.x; b0 = b0 > 0.f ? b0 : NEG_ * b0;
            float b1 = a5.y + ad.y + ae.y; b1 = b1 > 0.f ? b1 : NEG_ * b1;
            float b2 = a5.z + ad.z + ae.z; b2 = b2 > 0.f ? b2 : NEG_ * b2;
            float b3 = a5.w + ad.w + ae.w; b3 = b3 > 0.f ? b3 : NEG_ * b3;
            ex = make_float4(__expf(b0), __expf(b1), __expf(b2), __expf(b3));
        }
        const float* xp = xh + (long)s * 256;
        acc += ex.x * i0 * xp[lane] + ex.y * i1 * xp[64 + lane]
             + ex.z * i2 * xp[128 + lane] + ex.w * i3 * xp[192 + lane];
    }
    // self-loop contribution
    {
        const float* xp = xh + (long)n * 256;
        acc += exs.x * i0 * xp[lane] + exs.y * i1 * xp[64 + lane]
             + exs.z * i2 * xp[128 + lane] + exs.w * i3 * xp[192 + lane];
    }
    x1[(long)n * 64 + lane] = acc * 0.25f + gat_bias[lane];
}

// ---------- BN stats (read-only) ----------
__global__ __launch_bounds__(256) void k_x1stats(
    const float* __restrict__ x1, float* __restrict__ bnsum) {
    int c = threadIdx.x & 63, r = threadIdx.x >> 6;
    float s = 0.f, s2 = 0.f;
    for (int n = blockIdx.x * 4 + r; n < N_; n += gridDim.x * 4) {
        float v = x1[(long)n * 64 + c];
        s += v; s2 += v * v;
    }
    __shared__ float red[4][128];
    red[r][c] = s; red[r][64 + c] = s2;
    __syncthreads();
    if (r == 0) {
        float ts = red[0][c] + red[1][c] + red[2][c] + red[3][c];
        float t2 = red[0][64 + c] + red[1][64 + c] + red[2][64 + c] + red[3][64 + c];
        atomicAdd(&bnsum[c], ts);
        atomicAdd(&bnsum[64 + c], t2);
    }
}

__global__ void k_bnfin(const float* __restrict__ bnsum, const float* __restrict__ gamma,
                        const float* __restrict__ beta, float* __restrict__ bnp) {
    int c = threadIdx.x;
    float mu = bnsum[c] / (float)N_;
    float var = bnsum[64 + c] / (float)N_ - mu * mu;
    float sc = gamma[c] * rsqrtf(var + EPS_);
    bnp[c] = sc;
    bnp[64 + c] = beta[c] - mu * sc;
}

// ---------- LSTM via MFMA: 1 wave per 32 nodes (unchanged from round 4) ----------
__global__ __launch_bounds__(64, 1) void k_lstm_mfma(
    const float* __restrict__ xdyn, const float* __restrict__ W_ih,
    const float* __restrict__ W_hh, const float* __restrict__ b_ih,
    const float* __restrict__ b_hh, float* __restrict__ hlast) {
    __shared__ short Hl[32 * 64];
    char* Hb = (char*)Hl;
    const int l = threadIdx.x;
    const int lm = l & 31;
    const int g  = l >> 5;
    const int nbase = blockIdx.x * 32;

    short8v Bh[8][4];
#pragma unroll
    for (int t8 = 0; t8 < 8; ++t8) {
#pragma unroll
        for (int ks = 0; ks < 4; ++ks) {
            int j = 32 * t8 + lm;
            const float* wp = W_hh + j * 64 + 16 * ks + 8 * g;
            float4 wa = *(const float4*)wp;
            float4 wb = *(const float4*)(wp + 4);
            short8v f;
            f[0] = f2bf(wa.x); f[1] = f2bf(wa.y); f[2] = f2bf(wa.z); f[3] = f2bf(wa.w);
            f[4] = f2bf(wb.x); f[5] = f2bf(wb.y); f[6] = f2bf(wb.z); f[7] = f2bf(wb.w);
            Bh[t8][ks] = f;
        }
    }
    short8v B2[8];
#pragma unroll
    for (int t8 = 0; t8 < 8; ++t8) {
        int j = 32 * t8 + lm;
        short8v f;
        if (g == 0) {
            const float* wp = W_ih + j * 8;
            float4 wa = *(const float4*)wp;
            float4 wb = *(const float4*)(wp + 4);
            f[0] = f2bf(wa.x); f[1] = f2bf(wa.y); f[2] = f2bf(wa.z); f[3] = f2bf(wa.w);
            f[4] = f2bf(wb.x); f[5] = f2bf(wb.y); f[6] = f2bf(wb.z); f[7] = f2bf(wb.w);
        } else {
#pragma unroll
            for (int e = 0; e < 8; ++e) f[e] = 0;
            f[0] = f2bf(b_ih[j] + b_hh[j]);
        }
        B2[t8] = f;
    }
    short8v xAc;
#pragma unroll
    for (int e = 0; e < 8; ++e) xAc[e] = 0;
    xAc[0] = (short)0x3F80;

    f32x16 zc;
#pragma unroll
    for (int e = 0; e < 16; ++e) zc[e] = 0.f;

    {
        short8v zv;
#pragma unroll
        for (int e = 0; e < 8; ++e) zv[e] = 0;
#pragma unroll
        for (int i = l; i < 256; i += 64) ((short8v*)Hl)[i] = zv;
    }
    float cst[2][16];
#pragma unroll
    for (int jt = 0; jt < 2; ++jt)
#pragma unroll
        for (int r = 0; r < 16; ++r) cst[jt][r] = 0.f;

    __syncthreads();

    const float* xbase = xdyn + (long)(nbase + lm) * T_ * 8;
    float4 xp0, xp1;
    if (g == 0) { xp0 = *(const float4*)xbase; xp1 = *(const float4*)(xbase + 4); }

    for (int t = 0; t < T_; ++t) {
        short8v xA;
        if (g == 0) {
            xA[0] = f2bf(xp0.x); xA[1] = f2bf(xp0.y); xA[2] = f2bf(xp0.z); xA[3] = f2bf(xp0.w);
            xA[4] = f2bf(xp1.x); xA[5] = f2bf(xp1.y); xA[6] = f2bf(xp1.z); xA[7] = f2bf(xp1.w);
            if (t < T_ - 1) {
                xp0 = *(const float4*)(xbase + (t + 1) * 8);
                xp1 = *(const float4*)(xbase + (t + 1) * 8 + 4);
            }
        } else xA = xAc;

        f32x16 acc[8];
#pragma unroll
        for (int t8 = 0; t8 < 8; ++t8)
            acc[t8] = __builtin_amdgcn_mfma_f32_32x32x16_bf16(xA, B2[t8], zc, 0, 0, 0);

        short8v hA[4];
#pragma unroll
        for (int ks = 0; ks < 4; ++ks) {
            int raddr = (lm * 128 + 32 * ks + 16 * g) ^ ((lm & 7) << 4);
            hA[ks] = *(const short8v*)(Hb + raddr);
        }
#pragma unroll
        for (int ks = 0; ks < 4; ++ks)
#pragma unroll
            for (int t8 = 0; t8 < 8; ++t8)
                acc[t8] = __builtin_amdgcn_mfma_f32_32x32x16_bf16(hA[ks], Bh[t8][ks], acc[t8], 0, 0, 0);

        __syncthreads();

#pragma unroll
        for (int jt = 0; jt < 2; ++jt) {
#pragma unroll
            for (int r = 0; r < 16; ++r) {
                float iv = acc[jt][r];
                float fv = acc[2 + jt][r];
                float gv = acc[4 + jt][r];
                float ov = acc[6 + jt][r];
                float si = sigf(iv), sf = sigf(fv), tg = tanhfast(gv), so = sigf(ov);
                float cn = sf * cst[jt][r] + si * tg;
                cst[jt][r] = cn;
                float hn = so * tanhfast(cn);
                int mrow = (r & 3) + 8 * (r >> 2) + 4 * g;
                int j = 32 * jt + lm;
                int waddr = (mrow * 128 + j * 2) ^ ((mrow & 7) << 4);
                *(short*)(Hb + waddr) = f2bf(hn);
                if (t == T_ - 1) hlast[(long)(nbase + mrow) * 64 + j] = hn;
            }
        }
        __syncthreads();
    }
}

// ---------- head: BN-relu(x1) ++ h_last -> hidden -> out ----------
__global__ __launch_bounds__(256) void k_head(
    const float* __restrict__ x1, const float* __restrict__ hlast,
    const float* __restrict__ bnp, const float* __restrict__ W_hid,
    const float* __restrict__ b_hid, const float* __restrict__ W_out,
    const float* __restrict__ b_out, float* __restrict__ out) {
    int n = blockIdx.x * 256 + threadIdx.x;
    if (n >= N_) return;
    float comb[128];
#pragma unroll
    for (int i = 0; i < 64; ++i)
        comb[i] = fmaxf(x1[(long)n * 64 + i] * bnp[i] + bnp[64 + i], 0.f);
#pragma unroll
    for (int i = 0; i < 64; ++i) comb[64 + i] = hlast[(long)n * 64 + i];
    float o = b_out[0];
    for (int j = 0; j < 32; ++j) {
        float a = b_hid[j];
#pragma unroll
        for (int i = 0; i < 128; ++i) a += comb[i] * W_hid[i * 32 + j];
        o += fmaxf(a, 0.f) * W_out[j];
    }
    out[n] = o;
}

extern "C" void kernel_launch(void* const* d_in, const int* in_sizes, int n_in,
                              void* d_out, int out_size, void* d_ws, size_t ws_size,
                              hipStream_t stream) {
    const float* x_node   = (const float*)d_in[0];
    const float* ea       = (const float*)d_in[1];
    const float* xdyn     = (const float*)d_in[2];
    const int*   eidx     = (const int*)d_in[3];
    const float* W_lin    = (const float*)d_in[4];
    const float* W_edge   = (const float*)d_in[5];
    const float* att_src  = (const float*)d_in[6];
    const float* att_dst  = (const float*)d_in[7];
    const float* att_edge = (const float*)d_in[8];
    const float* gat_bias = (const float*)d_in[9];
    const float* bn_gamma = (const float*)d_in[10];
    const float* bn_beta  = (const float*)d_in[11];
    const float* W_ih     = (const float*)d_in[12];
    const float* W_hh     = (const float*)d_in[13];
    const float* b_ih     = (const float*)d_in[14];
    const float* b_hh     = (const float*)d_in[15];
    const float* W_hid    = (const float*)d_in[16];
    const float* b_hid    = (const float*)d_in[17];
    const float* W_out    = (const float*)d_in[18];
    const float* b_out    = (const float*)d_in[19];
    float* out = (float*)d_out;

    char* ws = (char*)d_ws;
    size_t off = 0;
    auto alloc = [&](size_t bytes) -> void* {
        void* p = ws + off;
        off = (off + bytes + 255) & ~(size_t)255;
        return p;
    };
    int*      flag  = (int*)alloc(4);
    float*    P     = (float*)alloc(256 * 4);
    float*    bnp   = (float*)alloc(128 * 4);
    char*     zs    = ws + off;                       // ---- zero region start
    float*    bnsum = (float*)alloc(128 * 4);
    int*      degi  = (int*)alloc((size_t)N_ * 4);
    int*      cursor= (int*)alloc((size_t)N_ * 4);
    size_t zbytes = (size_t)((ws + off) - zs);        // ---- zero region end
    int*      offs  = (int*)alloc((size_t)N_ * 4);
    float4*   aebuf = (float4*)alloc((size_t)E_ * 16);
    int2*     csr   = (int2*)alloc((size_t)E_ * 8);
    float*    xh    = (float*)alloc((size_t)N_ * 256 * 4);
    float*    asrc  = (float*)alloc((size_t)N_ * 4 * 4);
    float*    adst  = (float*)alloc((size_t)N_ * 4 * 4);
    float*    x1    = (float*)alloc((size_t)N_ * 64 * 4);
    float*    hlast = (float*)alloc((size_t)N_ * 64 * 4);
    (void)ws_size; (void)in_sizes; (void)n_in; (void)out_size;

    hipMemsetAsync(zs, 0, zbytes, stream);
    k_detect<<<1, 64, 0, stream>>>(eidx, flag);
    k_P<<<1, 64, 0, stream>>>(W_edge, att_edge, P);
    k_node<<<N_, 256, 0, stream>>>(x_node, W_lin, att_src, att_dst, xh, asrc, adst);
    k_e1<<<(E_ + 255) / 256, 256, 0, stream>>>(eidx, flag, ea, P, aebuf, degi);
    k_scan<<<1, 256, 0, stream>>>(degi, offs);
    k_e2<<<(E_ + 255) / 256, 256, 0, stream>>>(eidx, flag, offs, cursor, csr);
    k_n2<<<(N_ + 3) / 4, 256, 0, stream>>>(offs, degi, csr, aebuf,
                                           (const float4*)asrc, (const float4*)adst,
                                           xh, gat_bias, x1);
    k_x1stats<<<128, 256, 0, stream>>>(x1, bnsum);
    k_bnfin<<<1, 64, 0, stream>>>(bnsum, bn_gamma, bn_beta, bnp);
    k_lstm_mfma<<<N_ / 32, 64, 0, stream>>>(xdyn, W_ih, W_hh, b_ih, b_hh, hlast);
    k_head<<<(N_ + 255) / 256, 256, 0, stream>>>(x1, hlast, bnp, W_hid, b_hid, W_out, b_out, out);
}

// Round 6
// 514.852 us; speedup vs baseline: 3.7438x; 1.0417x over previous
//
#include <hip/hip_runtime.h>
#include <hip/hip_bf16.h>

constexpr int N_  = 20000;
constexpr int E_  = 320000;
constexpr int T_  = 24;
constexpr float NEG_ = 0.2f;
constexpr float EPS_ = 1e-5f;
constexpr int MAXD_ = 128;              // LDS edge-cache per node (fallback past this)
constexpr int LNB_ = 8;                 // nodes per wave in LSTM

typedef __attribute__((ext_vector_type(8)))  short short8v;
typedef __attribute__((ext_vector_type(16))) float f32x16;

// ---------- edge_index accessors (int32 vs int64 runtime-detected) ----------
__device__ __forceinline__ int esrc(const int* __restrict__ p, int e, int f64) {
    return f64 ? p[4 * e] : p[2 * e];
}
__device__ __forceinline__ int edst(const int* __restrict__ p, int e, int f64) {
    return f64 ? p[4 * e + 2] : p[2 * e + 1];
}

__device__ __forceinline__ float sigf(float x) {
    return 1.f / (1.f + __expf(-x));
}
__device__ __forceinline__ float tanhfast(float x) {
    return 1.f - 2.f / (1.f + __expf(2.f * x));
}

// f32 -> bf16 round-to-nearest-even
__device__ __forceinline__ short f2bf(float f) {
    union { float f; unsigned u; } v; v.f = f;
    unsigned r = v.u + 0x7FFFu + ((v.u >> 16) & 1u);
    return (short)(r >> 16);
}

// ---------- detect int64 vs int32 edge_index ----------
__global__ void k_detect(const int* __restrict__ idx, int* __restrict__ flag) {
    int v = idx[2 * threadIdx.x + 1];
    unsigned long long b = __ballot(v != 0);
    if (threadIdx.x == 0) flag[0] = (b == 0ULL) ? 1 : 0;
}

// ---------- P[k][h] = P^T precompute ; Q[k][q] = att projections of W_lin ----------
__global__ __launch_bounds__(256) void k_Pq(
    const float* __restrict__ W_edge, const float* __restrict__ att_edge,
    const float* __restrict__ att_src, const float* __restrict__ att_dst,
    const float* __restrict__ W_lin, float* __restrict__ P, float* __restrict__ Q) {
    int t = threadIdx.x;
    if (t < 64) {
        int k = t >> 2, h = t & 3;
        float s = 0.f;
        for (int c = 0; c < 64; ++c) s += W_edge[k * 256 + h * 64 + c] * att_edge[h * 64 + c];
        P[k * 4 + h] = s;
    }
    {
        int k = t >> 2, h = t & 3;      // k 0..63
        float s = 0.f, d = 0.f;
        for (int c = 0; c < 64; ++c) {
            float w = W_lin[k * 256 + h * 64 + c];
            s += w * att_src[h * 64 + c];
            d += w * att_dst[h * 64 + c];
        }
        Q[k * 8 + h] = s;
        Q[k * 8 + 4 + h] = d;
    }
}

// ---------- per-node: xh = x @ W_lin ; a_src/a_dst = x @ Q (16 nodes/block) ----------
__global__ __launch_bounds__(256) void k_node(
    const float* __restrict__ x, const float* __restrict__ W_lin,
    const float* __restrict__ Q,
    float* __restrict__ xh, float* __restrict__ asrc, float* __restrict__ adst) {
    __shared__ float xs[16][65];
    __shared__ float Qsh[64][8];
    int t = threadIdx.x;
    int nb = blockIdx.x * 16;
    for (int i = t; i < 16 * 64; i += 256) xs[i >> 6][i & 63] = x[(long)nb * 64 + i];
    for (int i = t; i < 64 * 8; i += 256) ((float*)Qsh)[i] = Q[i];
    __syncthreads();
    float acc[16];
#pragma unroll
    for (int m = 0; m < 16; ++m) acc[m] = 0.f;
    for (int k = 0; k < 64; ++k) {
        float w = W_lin[k * 256 + t];
#pragma unroll
        for (int m = 0; m < 16; ++m) acc[m] += xs[m][k] * w;
    }
#pragma unroll
    for (int m = 0; m < 16; ++m) xh[(long)(nb + m) * 256 + t] = acc[m];
    if (t < 128) {
        int m = t >> 3, q = t & 7;      // q: 0-3 src head, 4-7 dst head
        float s = 0.f;
        for (int k = 0; k < 64; ++k) s += xs[m][k] * Qsh[k][q];
        if (q < 4) asrc[(nb + m) * 4 + q] = s;
        else       adst[(nb + m) * 4 + (q - 4)] = s;
    }
}

// ---------- E1: ae[e][h] = P^T . ea[e] ; deg count ----------
__global__ __launch_bounds__(256) void k_e1(
    const int* __restrict__ idx, const int* __restrict__ flag,
    const float* __restrict__ ea, const float* __restrict__ P,
    float4* __restrict__ aebuf, int* __restrict__ degi) {
    __shared__ float Ps[256];
    int t = threadIdx.x;
    if (t < 64) Ps[t] = P[t];
    __syncthreads();
    int e = blockIdx.x * 256 + t;
    if (e >= E_) return;
    int f64 = flag[0];
    int d = edst(idx, e, f64);
    const float* ep = ea + (long)e * 16;
    float ae[4] = {0.f, 0.f, 0.f, 0.f};
#pragma unroll
    for (int k = 0; k < 16; ++k) {
        float v = ep[k];
#pragma unroll
        for (int h = 0; h < 4; ++h) ae[h] += v * Ps[k * 4 + h];
    }
    aebuf[e] = make_float4(ae[0], ae[1], ae[2], ae[3]);
    atomicAdd(&degi[d], 1);
}

// ---------- exclusive prefix scan of degi (single block) ----------
__global__ __launch_bounds__(256) void k_scan(const int* __restrict__ degi,
                                              int* __restrict__ offs) {
    __shared__ int part[256];
    int t = threadIdx.x;
    int base = t * 80;
    int s = 0;
    for (int i = 0; i < 80; ++i) { int ix = base + i; if (ix < N_) s += degi[ix]; }
    part[t] = s;
    __syncthreads();
    for (int d = 1; d < 256; d <<= 1) {
        int v = (t >= d) ? part[t - d] : 0;
        __syncthreads();
        part[t] += v;
        __syncthreads();
    }
    int run = (t > 0) ? part[t - 1] : 0;
    for (int i = 0; i < 80; ++i) {
        int ix = base + i;
        if (ix < N_) { offs[ix] = run; run += degi[ix]; }
    }
}

// ---------- E2: counting-sort edges into CSR (slot -> (edge, src)) ----------
__global__ __launch_bounds__(256) void k_e2(
    const int* __restrict__ idx, const int* __restrict__ flag,
    const int* __restrict__ offs, int* __restrict__ cursor,
    int2* __restrict__ csr) {
    int e = blockIdx.x * 256 + threadIdx.x;
    if (e >= E_) return;
    int f64 = flag[0];
    int d = edst(idx, e, f64);
    int s = esrc(idx, e, f64);
    int pos = atomicAdd(&cursor[d], 1);
    csr[offs[d] + pos] = make_int2(e, s);
}

// ---------- N2: per-dst softmax + gather (no atomics), fused x1 epilogue ----------
__global__ __launch_bounds__(256) void k_n2(
    const int* __restrict__ offs, const int* __restrict__ degi,
    const int2* __restrict__ csr, const float4* __restrict__ aebuf,
    const float4* __restrict__ asrc4, const float4* __restrict__ adst4,
    const float* __restrict__ xh, const float* __restrict__ gat_bias,
    float* __restrict__ x1) {
    __shared__ int   sS[4][MAXD_];
    __shared__ float4 sEx[4][MAXD_];
    int t = threadIdx.x, w = t >> 6, lane = t & 63;
    int n = blockIdx.x * 4 + w;
    if (n >= N_) return;
    int deg = degi[n], off = offs[n];
    float4 ad = adst4[n];

    float4 aesum = make_float4(0, 0, 0, 0), den = make_float4(0, 0, 0, 0);
    for (int base = 0; base < deg; base += 64) {
        int i = base + lane;
        if (i < deg) {
            int2 pr = csr[off + i];
            float4 ae = aebuf[pr.x];
            float4 as = asrc4[pr.y];
            float a0 = as.x + ad.x + ae.x; a0 = a0 > 0.f ? a0 : NEG_ * a0;
            float a1 = as.y + ad.y + ae.y; a1 = a1 > 0.f ? a1 : NEG_ * a1;
            float a2 = as.z + ad.z + ae.z; a2 = a2 > 0.f ? a2 : NEG_ * a2;
            float a3 = as.w + ad.w + ae.w; a3 = a3 > 0.f ? a3 : NEG_ * a3;
            float4 ex = make_float4(__expf(a0), __expf(a1), __expf(a2), __expf(a3));
            aesum.x += ae.x; aesum.y += ae.y; aesum.z += ae.z; aesum.w += ae.w;
            den.x += ex.x; den.y += ex.y; den.z += ex.z; den.w += ex.w;
            if (i < MAXD_) { sS[w][i] = pr.y; sEx[w][i] = ex; }
        }
    }
#pragma unroll
    for (int m = 32; m >= 1; m >>= 1) {
        aesum.x += __shfl_xor(aesum.x, m); aesum.y += __shfl_xor(aesum.y, m);
        aesum.z += __shfl_xor(aesum.z, m); aesum.w += __shfl_xor(aesum.w, m);
        den.x += __shfl_xor(den.x, m); den.y += __shfl_xor(den.y, m);
        den.z += __shfl_xor(den.z, m); den.w += __shfl_xor(den.w, m);
    }
    float dv = fmaxf((float)deg, 1.f);
    float4 as = asrc4[n];
    float a0 = as.x + ad.x + aesum.x / dv; a0 = a0 > 0.f ? a0 : NEG_ * a0;
    float a1 = as.y + ad.y + aesum.y / dv; a1 = a1 > 0.f ? a1 : NEG_ * a1;
    float a2 = as.z + ad.z + aesum.z / dv; a2 = a2 > 0.f ? a2 : NEG_ * a2;
    float a3 = as.w + ad.w + aesum.w / dv; a3 = a3 > 0.f ? a3 : NEG_ * a3;
    float4 exs = make_float4(__expf(a0), __expf(a1), __expf(a2), __expf(a3));
    den.x += exs.x; den.y += exs.y; den.z += exs.z; den.w += exs.w;
    float i0 = 1.f / (den.x + 1e-16f), i1 = 1.f / (den.y + 1e-16f);
    float i2 = 1.f / (den.z + 1e-16f), i3 = 1.f / (den.w + 1e-16f);
    __syncthreads();

    float acc = 0.f;
    for (int i = 0; i < deg; ++i) {
        int s; float4 ex;
        if (i < MAXD_) { s = sS[w][i]; ex = sEx[w][i]; }
        else {
            int2 pr = csr[off + i];
            s = pr.y;
            float4 ae = aebuf[pr.x];
            float4 a5 = asrc4[s];
            float b0 = a5.x + ad.x + ae.x; b0 = b0 > 0.f ? b0 : NEG_ * b0;
            float b1 = a5.y + ad.y + ae.y; b1 = b1 > 0.f ? b1 : NEG_ * b1;
            float b2 = a5.z + ad.z + ae.z; b2 = b2 > 0.f ? b2 : NEG_ * b2;
            float b3 = a5.w + ad.w + ae.w; b3 = b3 > 0.f ? b3 : NEG_ * b3;
            ex = make_float4(__expf(b0), __expf(b1), __expf(b2), __expf(b3));
        }
        const float* xp = xh + (long)s * 256;
        acc += ex.x * i0 * xp[lane] + ex.y * i1 * xp[64 + lane]
             + ex.z * i2 * xp[128 + lane] + ex.w * i3 * xp[192 + lane];
    }
    {
        const float* xp = xh + (long)n * 256;
        acc += exs.x * i0 * xp[lane] + exs.y * i1 * xp[64 + lane]
             + exs.z * i2 * xp[128 + lane] + exs.w * i3 * xp[192 + lane];
    }
    x1[(long)n * 64 + lane] = acc * 0.25f + gat_bias[lane];
}

// ---------- BN stats (read-only) ----------
__global__ __launch_bounds__(256) void k_x1stats(
    const float* __restrict__ x1, float* __restrict__ bnsum) {
    int c = threadIdx.x & 63, r = threadIdx.x >> 6;
    float s = 0.f, s2 = 0.f;
    for (int n = blockIdx.x * 4 + r; n < N_; n += gridDim.x * 4) {
        float v = x1[(long)n * 64 + c];
        s += v; s2 += v * v;
    }
    __shared__ float red[4][128];
    red[r][c] = s; red[r][64 + c] = s2;
    __syncthreads();
    if (r == 0) {
        float ts = red[0][c] + red[1][c] + red[2][c] + red[3][c];
        float t2 = red[0][64 + c] + red[1][64 + c] + red[2][64 + c] + red[3][64 + c];
        atomicAdd(&bnsum[c], ts);
        atomicAdd(&bnsum[64 + c], t2);
    }
}

__global__ void k_bnfin(const float* __restrict__ bnsum, const float* __restrict__ gamma,
                        const float* __restrict__ beta, float* __restrict__ bnp) {
    int c = threadIdx.x;
    float mu = bnsum[c] / (float)N_;
    float var = bnsum[64 + c] / (float)N_ - mu * mu;
    float sc = gamma[c] * rsqrtf(var + EPS_);
    bnp[c] = sc;
    bnp[64 + c] = beta[c] - mu * sc;
}

// ---------- LSTM via MFMA: 1 wave per LNB_ nodes (M-tile partially used) ----------
// gates[32 x 256] = [h(64) | x(8),1,pad] @ [W_hh^T ; W_ih^T ; bias] per step.
// Only C rows < LNB_ are valid; rows LNB_..31 of H stay zero.
__global__ __launch_bounds__(64, 1) void k_lstm_mfma(
    const float* __restrict__ xdyn, const float* __restrict__ W_ih,
    const float* __restrict__ W_hh, const float* __restrict__ b_ih,
    const float* __restrict__ b_hh, float* __restrict__ hlast) {
    __shared__ short Hl[32 * 64];        // full 32 rows, rows >= LNB_ stay 0
    char* Hb = (char*)Hl;
    const int l = threadIdx.x;
    const int lm = l & 31;
    const int g  = l >> 5;
    const int nbase = blockIdx.x * LNB_;

    short8v Bh[8][4];
#pragma unroll
    for (int t8 = 0; t8 < 8; ++t8) {
#pragma unroll
        for (int ks = 0; ks < 4; ++ks) {
            int j = 32 * t8 + lm;
            const float* wp = W_hh + j * 64 + 16 * ks + 8 * g;
            float4 wa = *(const float4*)wp;
            float4 wb = *(const float4*)(wp + 4);
            short8v f;
            f[0] = f2bf(wa.x); f[1] = f2bf(wa.y); f[2] = f2bf(wa.z); f[3] = f2bf(wa.w);
            f[4] = f2bf(wb.x); f[5] = f2bf(wb.y); f[6] = f2bf(wb.z); f[7] = f2bf(wb.w);
            Bh[t8][ks] = f;
        }
    }
    short8v B2[8];
#pragma unroll
    for (int t8 = 0; t8 < 8; ++t8) {
        int j = 32 * t8 + lm;
        short8v f;
        if (g == 0) {
            const float* wp = W_ih + j * 8;
            float4 wa = *(const float4*)wp;
            float4 wb = *(const float4*)(wp + 4);
            f[0] = f2bf(wa.x); f[1] = f2bf(wa.y); f[2] = f2bf(wa.z); f[3] = f2bf(wa.w);
            f[4] = f2bf(wb.x); f[5] = f2bf(wb.y); f[6] = f2bf(wb.z); f[7] = f2bf(wb.w);
        } else {
#pragma unroll
            for (int e = 0; e < 8; ++e) f[e] = 0;
            f[0] = f2bf(b_ih[j] + b_hh[j]);
        }
        B2[t8] = f;
    }
    short8v xAc;
#pragma unroll
    for (int e = 0; e < 8; ++e) xAc[e] = 0;
    xAc[0] = (short)0x3F80;

    f32x16 zc;
#pragma unroll
    for (int e = 0; e < 16; ++e) zc[e] = 0.f;

    {
        short8v zv;
#pragma unroll
        for (int e = 0; e < 8; ++e) zv[e] = 0;
#pragma unroll
        for (int i = l; i < 256; i += 64) ((short8v*)Hl)[i] = zv;
    }
    float cst[2][4];
#pragma unroll
    for (int jt = 0; jt < 2; ++jt)
#pragma unroll
        for (int r = 0; r < 4; ++r) cst[jt][r] = 0.f;

    __syncthreads();

    int xrow = nbase + lm;
    if (xrow >= N_) xrow = N_ - 1;       // clamp (last blocks' lanes >= LNB_)
    const float* xbase = xdyn + (long)xrow * T_ * 8;
    float4 xp0, xp1;
    if (g == 0) { xp0 = *(const float4*)xbase; xp1 = *(const float4*)(xbase + 4); }

    for (int t = 0; t < T_; ++t) {
        short8v xA;
        if (g == 0) {
            xA[0] = f2bf(xp0.x); xA[1] = f2bf(xp0.y); xA[2] = f2bf(xp0.z); xA[3] = f2bf(xp0.w);
            xA[4] = f2bf(xp1.x); xA[5] = f2bf(xp1.y); xA[6] = f2bf(xp1.z); xA[7] = f2bf(xp1.w);
            if (t < T_ - 1) {
                xp0 = *(const float4*)(xbase + (t + 1) * 8);
                xp1 = *(const float4*)(xbase + (t + 1) * 8 + 4);
            }
        } else xA = xAc;

        f32x16 acc[8];
#pragma unroll
        for (int t8 = 0; t8 < 8; ++t8)
            acc[t8] = __builtin_amdgcn_mfma_f32_32x32x16_bf16(xA, B2[t8], zc, 0, 0, 0);

        short8v hA[4];
#pragma unroll
        for (int ks = 0; ks < 4; ++ks) {
            int raddr = (lm * 128 + 32 * ks + 16 * g) ^ ((lm & 7) << 4);
            hA[ks] = *(const short8v*)(Hb + raddr);
        }
#pragma unroll
        for (int ks = 0; ks < 4; ++ks)
#pragma unroll
            for (int t8 = 0; t8 < 8; ++t8)
                acc[t8] = __builtin_amdgcn_mfma_f32_32x32x16_bf16(hA[ks], Bh[t8][ks], acc[t8], 0, 0, 0);

        __syncthreads();

        // only C rows mrow = r + 4g (r<4) < 8 are valid nodes
#pragma unroll
        for (int jt = 0; jt < 2; ++jt) {
#pragma unroll
            for (int r = 0; r < 4; ++r) {
                float iv = acc[jt][r];
                float fv = acc[2 + jt][r];
                float gv = acc[4 + jt][r];
                float ov = acc[6 + jt][r];
                float si = sigf(iv), sf = sigf(fv), tg = tanhfast(gv), so = sigf(ov);
                float cn = sf * cst[jt][r] + si * tg;
                cst[jt][r] = cn;
                float hn = so * tanhfast(cn);
                int mrow = r + 4 * g;
                int j = 32 * jt + lm;
                int waddr = (mrow * 128 + j * 2) ^ ((mrow & 7) << 4);
                *(short*)(Hb + waddr) = f2bf(hn);
                if (t == T_ - 1) hlast[(long)(nbase + mrow) * 64 + j] = hn;
            }
        }
        __syncthreads();
    }
}

// ---------- head: BN-relu(x1) ++ h_last -> hidden -> out ----------
__global__ __launch_bounds__(256) void k_head(
    const float* __restrict__ x1, const float* __restrict__ hlast,
    const float* __restrict__ bnp, const float* __restrict__ W_hid,
    const float* __restrict__ b_hid, const float* __restrict__ W_out,
    const float* __restrict__ b_out, float* __restrict__ out) {
    int n = blockIdx.x * 256 + threadIdx.x;
    if (n >= N_) return;
    float comb[128];
#pragma unroll
    for (int i = 0; i < 64; ++i)
        comb[i] = fmaxf(x1[(long)n * 64 + i] * bnp[i] + bnp[64 + i], 0.f);
#pragma unroll
    for (int i = 0; i < 64; ++i) comb[64 + i] = hlast[(long)n * 64 + i];
    float o = b_out[0];
    for (int j = 0; j < 32; ++j) {
        float a = b_hid[j];
#pragma unroll
        for (int i = 0; i < 128; ++i) a += comb[i] * W_hid[i * 32 + j];
        o += fmaxf(a, 0.f) * W_out[j];
    }
    out[n] = o;
}

extern "C" void kernel_launch(void* const* d_in, const int* in_sizes, int n_in,
                              void* d_out, int out_size, void* d_ws, size_t ws_size,
                              hipStream_t stream) {
    const float* x_node   = (const float*)d_in[0];
    const float* ea       = (const float*)d_in[1];
    const float* xdyn     = (const float*)d_in[2];
    const int*   eidx     = (const int*)d_in[3];
    const float* W_lin    = (const float*)d_in[4];
    const float* W_edge   = (const float*)d_in[5];
    const float* att_src  = (const float*)d_in[6];
    const float* att_dst  = (const float*)d_in[7];
    const float* att_edge = (const float*)d_in[8];
    const float* gat_bias = (const float*)d_in[9];
    const float* bn_gamma = (const float*)d_in[10];
    const float* bn_beta  = (const float*)d_in[11];
    const float* W_ih     = (const float*)d_in[12];
    const float* W_hh     = (const float*)d_in[13];
    const float* b_ih     = (const float*)d_in[14];
    const float* b_hh     = (const float*)d_in[15];
    const float* W_hid    = (const float*)d_in[16];
    const float* b_hid    = (const float*)d_in[17];
    const float* W_out    = (const float*)d_in[18];
    const float* b_out    = (const float*)d_in[19];
    float* out = (float*)d_out;

    char* ws = (char*)d_ws;
    size_t off = 0;
    auto alloc = [&](size_t bytes) -> void* {
        void* p = ws + off;
        off = (off + bytes + 255) & ~(size_t)255;
        return p;
    };
    int*      flag  = (int*)alloc(4);
    float*    P     = (float*)alloc(256 * 4);
    float*    Q     = (float*)alloc(64 * 8 * 4);
    float*    bnp   = (float*)alloc(128 * 4);
    char*     zs    = ws + off;                       // ---- zero region start
    float*    bnsum = (float*)alloc(128 * 4);
    int*      degi  = (int*)alloc((size_t)N_ * 4);
    int*      cursor= (int*)alloc((size_t)N_ * 4);
    size_t zbytes = (size_t)((ws + off) - zs);        // ---- zero region end
    int*      offs  = (int*)alloc((size_t)N_ * 4);
    float4*   aebuf = (float4*)alloc((size_t)E_ * 16);
    int2*     csr   = (int2*)alloc((size_t)E_ * 8);
    float*    xh    = (float*)alloc((size_t)N_ * 256 * 4);
    float*    asrc  = (float*)alloc((size_t)N_ * 4 * 4);
    float*    adst  = (float*)alloc((size_t)N_ * 4 * 4);
    float*    x1    = (float*)alloc((size_t)N_ * 64 * 4);
    float*    hlast = (float*)alloc((size_t)N_ * 64 * 4);
    (void)ws_size; (void)in_sizes; (void)n_in; (void)out_size;

    hipMemsetAsync(zs, 0, zbytes, stream);
    k_detect<<<1, 64, 0, stream>>>(eidx, flag);
    k_Pq<<<1, 256, 0, stream>>>(W_edge, att_edge, att_src, att_dst, W_lin, P, Q);
    k_node<<<N_ / 16, 256, 0, stream>>>(x_node, W_lin, Q, xh, asrc, adst);
    k_e1<<<(E_ + 255) / 256, 256, 0, stream>>>(eidx, flag, ea, P, aebuf, degi);
    k_scan<<<1, 256, 0, stream>>>(degi, offs);
    k_e2<<<(E_ + 255) / 256, 256, 0, stream>>>(eidx, flag, offs, cursor, csr);
    k_n2<<<(N_ + 3) / 4, 256, 0, stream>>>(offs, degi, csr, aebuf,
                                           (const float4*)asrc, (const float4*)adst,
                                           xh, gat_bias, x1);
    k_x1stats<<<128, 256, 0, stream>>>(x1, bnsum);
    k_bnfin<<<1, 64, 0, stream>>>(bnsum, bn_gamma, bn_beta, bnp);
    k_lstm_mfma<<<(N_ + LNB_ - 1) / LNB_, 64, 0, stream>>>(xdyn, W_ih, W_hh, b_ih, b_hh, hlast);
    k_head<<<(N_ + 255) / 256, 256, 0, stream>>>(x1, hlast, bnp, W_hid, b_hid, W_out, b_out, out);
}

// Round 8
// 469.706 us; speedup vs baseline: 4.1036x; 1.0961x over previous
//
#include <hip/hip_runtime.h>
#include <hip/hip_bf16.h>

constexpr int N_  = 20000;
constexpr int E_  = 320000;
constexpr int T_  = 24;
constexpr float NEG_ = 0.2f;
constexpr float EPS_ = 1e-5f;
constexpr int MAXD_ = 128;              // LDS edge-cache per node (fallback past this)
constexpr int LNB_ = 8;                 // nodes per wave in LSTM

typedef __attribute__((ext_vector_type(8)))  short short8v;
typedef __attribute__((ext_vector_type(16))) float f32x16;

// ---------- edge_index accessors (int32 vs int64 runtime-detected) ----------
__device__ __forceinline__ int esrc(const int* __restrict__ p, int e, int f64) {
    return f64 ? p[4 * e] : p[2 * e];
}
__device__ __forceinline__ int edst(const int* __restrict__ p, int e, int f64) {
    return f64 ? p[4 * e + 2] : p[2 * e + 1];
}

// fast gate math: v_rcp_f32 (1 ulp) instead of full-precision f32 division
__device__ __forceinline__ float sigf(float x) {
    return __builtin_amdgcn_rcpf(1.f + __expf(-x));
}
__device__ __forceinline__ float tanhfast(float x) {
    return 1.f - 2.f * __builtin_amdgcn_rcpf(1.f + __expf(2.f * x));
}

// f32 -> bf16 round-to-nearest-even
__device__ __forceinline__ short f2bf(float f) {
    union { float f; unsigned u; } v; v.f = f;
    unsigned r = v.u + 0x7FFFu + ((v.u >> 16) & 1u);
    return (short)(r >> 16);
}

// ---------- detect int64 vs int32 edge_index ----------
__global__ void k_detect(const int* __restrict__ idx, int* __restrict__ flag) {
    int v = idx[2 * threadIdx.x + 1];
    unsigned long long b = __ballot(v != 0);
    if (threadIdx.x == 0) flag[0] = (b == 0ULL) ? 1 : 0;
}

// ---------- P[k][h] = P^T precompute ; Q[k][q] = att projections of W_lin ----------
__global__ __launch_bounds__(256) void k_Pq(
    const float* __restrict__ W_edge, const float* __restrict__ att_edge,
    const float* __restrict__ att_src, const float* __restrict__ att_dst,
    const float* __restrict__ W_lin, float* __restrict__ P, float* __restrict__ Q) {
    int t = threadIdx.x;
    if (t < 64) {
        int k = t >> 2, h = t & 3;
        float s = 0.f;
        for (int c = 0; c < 64; ++c) s += W_edge[k * 256 + h * 64 + c] * att_edge[h * 64 + c];
        P[k * 4 + h] = s;
    }
    {
        int k = t >> 2, h = t & 3;      // k 0..63
        float s = 0.f, d = 0.f;
        for (int c = 0; c < 64; ++c) {
            float w = W_lin[k * 256 + h * 64 + c];
            s += w * att_src[h * 64 + c];
            d += w * att_dst[h * 64 + c];
        }
        Q[k * 8 + h] = s;
        Q[k * 8 + 4 + h] = d;
    }
}

// ---------- per-node: xh = x @ W_lin ; a_src/a_dst = x @ Q (16 nodes/block) ----------
__global__ __launch_bounds__(256) void k_node(
    const float* __restrict__ x, const float* __restrict__ W_lin,
    const float* __restrict__ Q,
    float* __restrict__ xh, float* __restrict__ asrc, float* __restrict__ adst) {
    __shared__ float xs[16][65];
    __shared__ float Qsh[64][8];
    int t = threadIdx.x;
    int nb = blockIdx.x * 16;
    for (int i = t; i < 16 * 64; i += 256) xs[i >> 6][i & 63] = x[(long)nb * 64 + i];
    for (int i = t; i < 64 * 8; i += 256) ((float*)Qsh)[i] = Q[i];
    __syncthreads();
    float acc[16];
#pragma unroll
    for (int m = 0; m < 16; ++m) acc[m] = 0.f;
    for (int k = 0; k < 64; ++k) {
        float w = W_lin[k * 256 + t];
#pragma unroll
        for (int m = 0; m < 16; ++m) acc[m] += xs[m][k] * w;
    }
#pragma unroll
    for (int m = 0; m < 16; ++m) xh[(long)(nb + m) * 256 + t] = acc[m];
    if (t < 128) {
        int m = t >> 3, q = t & 7;      // q: 0-3 src head, 4-7 dst head
        float s = 0.f;
        for (int k = 0; k < 64; ++k) s += xs[m][k] * Qsh[k][q];
        if (q < 4) asrc[(nb + m) * 4 + q] = s;
        else       adst[(nb + m) * 4 + (q - 4)] = s;
    }
}

// ---------- E1: ae[e][h] = P^T . ea[e] ; deg count ----------
__global__ __launch_bounds__(256) void k_e1(
    const int* __restrict__ idx, const int* __restrict__ flag,
    const float* __restrict__ ea, const float* __restrict__ P,
    float4* __restrict__ aebuf, int* __restrict__ degi) {
    __shared__ float Ps[256];
    int t = threadIdx.x;
    if (t < 64) Ps[t] = P[t];
    __syncthreads();
    int e = blockIdx.x * 256 + t;
    if (e >= E_) return;
    int f64 = flag[0];
    int d = edst(idx, e, f64);
    const float* ep = ea + (long)e * 16;
    float ae[4] = {0.f, 0.f, 0.f, 0.f};
#pragma unroll
    for (int k = 0; k < 16; ++k) {
        float v = ep[k];
#pragma unroll
        for (int h = 0; h < 4; ++h) ae[h] += v * Ps[k * 4 + h];
    }
    aebuf[e] = make_float4(ae[0], ae[1], ae[2], ae[3]);
    atomicAdd(&degi[d], 1);
}

// ---------- exclusive prefix scan of degi (single block) ----------
__global__ __launch_bounds__(256) void k_scan(const int* __restrict__ degi,
                                              int* __restrict__ offs) {
    __shared__ int part[256];
    int t = threadIdx.x;
    int base = t * 80;
    int s = 0;
    for (int i = 0; i < 80; ++i) { int ix = base + i; if (ix < N_) s += degi[ix]; }
    part[t] = s;
    __syncthreads();
    for (int d = 1; d < 256; d <<= 1) {
        int v = (t >= d) ? part[t - d] : 0;
        __syncthreads();
        part[t] += v;
        __syncthreads();
    }
    int run = (t > 0) ? part[t - 1] : 0;
    for (int i = 0; i < 80; ++i) {
        int ix = base + i;
        if (ix < N_) { offs[ix] = run; run += degi[ix]; }
    }
}

// ---------- E2: counting-sort edges into CSR (slot -> (edge, src)) ----------
__global__ __launch_bounds__(256) void k_e2(
    const int* __restrict__ idx, const int* __restrict__ flag,
    const int* __restrict__ offs, int* __restrict__ cursor,
    int2* __restrict__ csr) {
    int e = blockIdx.x * 256 + threadIdx.x;
    if (e >= E_) return;
    int f64 = flag[0];
    int d = edst(idx, e, f64);
    int s = esrc(idx, e, f64);
    int pos = atomicAdd(&cursor[d], 1);
    csr[offs[d] + pos] = make_int2(e, s);
}

// ---------- N2: per-dst softmax + gather (no atomics), fused x1 epilogue ----------
__global__ __launch_bounds__(256) void k_n2(
    const int* __restrict__ offs, const int* __restrict__ degi,
    const int2* __restrict__ csr, const float4* __restrict__ aebuf,
    const float4* __restrict__ asrc4, const float4* __restrict__ adst4,
    const float* __restrict__ xh, const float* __restrict__ gat_bias,
    float* __restrict__ x1) {
    __shared__ int   sS[4][MAXD_];
    __shared__ float4 sEx[4][MAXD_];
    int t = threadIdx.x, w = t >> 6, lane = t & 63;
    int n = blockIdx.x * 4 + w;
    if (n >= N_) return;
    int deg = degi[n], off = offs[n];
    float4 ad = adst4[n];

    float4 aesum = make_float4(0, 0, 0, 0), den = make_float4(0, 0, 0, 0);
    for (int base = 0; base < deg; base += 64) {
        int i = base + lane;
        if (i < deg) {
            int2 pr = csr[off + i];
            float4 ae = aebuf[pr.x];
            float4 as = asrc4[pr.y];
            float a0 = as.x + ad.x + ae.x; a0 = a0 > 0.f ? a0 : NEG_ * a0;
            float a1 = as.y + ad.y + ae.y; a1 = a1 > 0.f ? a1 : NEG_ * a1;
            float a2 = as.z + ad.z + ae.z; a2 = a2 > 0.f ? a2 : NEG_ * a2;
            float a3 = as.w + ad.w + ae.w; a3 = a3 > 0.f ? a3 : NEG_ * a3;
            float4 ex = make_float4(__expf(a0), __expf(a1), __expf(a2), __expf(a3));
            aesum.x += ae.x; aesum.y += ae.y; aesum.z += ae.z; aesum.w += ae.w;
            den.x += ex.x; den.y += ex.y; den.z += ex.z; den.w += ex.w;
            if (i < MAXD_) { sS[w][i] = pr.y; sEx[w][i] = ex; }
        }
    }
#pragma unroll
    for (int m = 32; m >= 1; m >>= 1) {
        aesum.x += __shfl_xor(aesum.x, m); aesum.y += __shfl_xor(aesum.y, m);
        aesum.z += __shfl_xor(aesum.z, m); aesum.w += __shfl_xor(aesum.w, m);
        den.x += __shfl_xor(den.x, m); den.y += __shfl_xor(den.y, m);
        den.z += __shfl_xor(den.z, m); den.w += __shfl_xor(den.w, m);
    }
    float dv = fmaxf((float)deg, 1.f);
    float4 as = asrc4[n];
    float a0 = as.x + ad.x + aesum.x / dv; a0 = a0 > 0.f ? a0 : NEG_ * a0;
    float a1 = as.y + ad.y + aesum.y / dv; a1 = a1 > 0.f ? a1 : NEG_ * a1;
    float a2 = as.z + ad.z + aesum.z / dv; a2 = a2 > 0.f ? a2 : NEG_ * a2;
    float a3 = as.w + ad.w + aesum.w / dv; a3 = a3 > 0.f ? a3 : NEG_ * a3;
    float4 exs = make_float4(__expf(a0), __expf(a1), __expf(a2), __expf(a3));
    den.x += exs.x; den.y += exs.y; den.z += exs.z; den.w += exs.w;
    float i0 = 1.f / (den.x + 1e-16f), i1 = 1.f / (den.y + 1e-16f);
    float i2 = 1.f / (den.z + 1e-16f), i3 = 1.f / (den.w + 1e-16f);
    __syncthreads();

    float acc = 0.f;
    for (int i = 0; i < deg; ++i) {
        int s; float4 ex;
        if (i < MAXD_) { s = sS[w][i]; ex = sEx[w][i]; }
        else {
            int2 pr = csr[off + i];
            s = pr.y;
            float4 ae = aebuf[pr.x];
            float4 a5 = asrc4[s];
            float b0 = a5.x + ad.x + ae.x; b0 = b0 > 0.f ? b0 : NEG_ * b0;
            float b1 = a5.y + ad.y + ae.y; b1 = b1 > 0.f ? b1 : NEG_ * b1;
            float b2 = a5.z + ad.z + ae.z; b2 = b2 > 0.f ? b2 : NEG_ * b2;
            float b3 = a5.w + ad.w + ae.w; b3 = b3 > 0.f ? b3 : NEG_ * b3;
            ex = make_float4(__expf(b0), __expf(b1), __expf(b2), __expf(b3));
        }
        const float* xp = xh + (long)s * 256;
        acc += ex.x * i0 * xp[lane] + ex.y * i1 * xp[64 + lane]
             + ex.z * i2 * xp[128 + lane] + ex.w * i3 * xp[192 + lane];
    }
    {
        const float* xp = xh + (long)n * 256;
        acc += exs.x * i0 * xp[lane] + exs.y * i1 * xp[64 + lane]
             + exs.z * i2 * xp[128 + lane] + exs.w * i3 * xp[192 + lane];
    }
    x1[(long)n * 64 + lane] = acc * 0.25f + gat_bias[lane];
}

// ---------- BN stats (read-only) ----------
__global__ __launch_bounds__(256) void k_x1stats(
    const float* __restrict__ x1, float* __restrict__ bnsum) {
    int c = threadIdx.x & 63, r = threadIdx.x >> 6;
    float s = 0.f, s2 = 0.f;
    for (int n = blockIdx.x * 4 + r; n < N_; n += gridDim.x * 4) {
        float v = x1[(long)n * 64 + c];
        s += v; s2 += v * v;
    }
    __shared__ float red[4][128];
    red[r][c] = s; red[r][64 + c] = s2;
    __syncthreads();
    if (r == 0) {
        float ts = red[0][c] + red[1][c] + red[2][c] + red[3][c];
        float t2 = red[0][64 + c] + red[1][64 + c] + red[2][64 + c] + red[3][64 + c];
        atomicAdd(&bnsum[c], ts);
        atomicAdd(&bnsum[64 + c], t2);
    }
}

__global__ void k_bnfin(const float* __restrict__ bnsum, const float* __restrict__ gamma,
                        const float* __restrict__ beta, float* __restrict__ bnp) {
    int c = threadIdx.x;
    float mu = bnsum[c] / (float)N_;
    float var = bnsum[64 + c] / (float)N_ - mu * mu;
    float sc = gamma[c] * rsqrtf(var + EPS_);
    bnp[c] = sc;
    bnp[64 + c] = beta[c] - mu * sc;
}

// ---------- LSTM via MFMA: 1 wave per LNB_ nodes (M-tile partially used) ----------
// gates[32 x 256] = [h(64) | x(8),1,pad] @ [W_hh^T ; W_ih^T ; bias] per step.
// Only C rows < LNB_ are valid; rows LNB_..31 of H stay zero; A rows >= LNB_
// get zero x-fragments (no wasted loads).
__global__ __launch_bounds__(64, 1) void k_lstm_mfma(
    const float* __restrict__ xdyn, const float* __restrict__ W_ih,
    const float* __restrict__ W_hh, const float* __restrict__ b_ih,
    const float* __restrict__ b_hh, float* __restrict__ hlast) {
    __shared__ short Hl[32 * 64];        // full 32 rows, rows >= LNB_ stay 0
    char* Hb = (char*)Hl;
    const int l = threadIdx.x;
    const int lm = l & 31;
    const int g  = l >> 5;
    const int nbase = blockIdx.x * LNB_;

    short8v Bh[8][4];
#pragma unroll
    for (int t8 = 0; t8 < 8; ++t8) {
#pragma unroll
        for (int ks = 0; ks < 4; ++ks) {
            int j = 32 * t8 + lm;
            const float* wp = W_hh + j * 64 + 16 * ks + 8 * g;
            float4 wa = *(const float4*)wp;
            float4 wb = *(const float4*)(wp + 4);
            short8v f;
            f[0] = f2bf(wa.x); f[1] = f2bf(wa.y); f[2] = f2bf(wa.z); f[3] = f2bf(wa.w);
            f[4] = f2bf(wb.x); f[5] = f2bf(wb.y); f[6] = f2bf(wb.z); f[7] = f2bf(wb.w);
            Bh[t8][ks] = f;
        }
    }
    short8v B2[8];
#pragma unroll
    for (int t8 = 0; t8 < 8; ++t8) {
        int j = 32 * t8 + lm;
        short8v f;
        if (g == 0) {
            const float* wp = W_ih + j * 8;
            float4 wa = *(const float4*)wp;
            float4 wb = *(const float4*)(wp + 4);
            f[0] = f2bf(wa.x); f[1] = f2bf(wa.y); f[2] = f2bf(wa.z); f[3] = f2bf(wa.w);
            f[4] = f2bf(wb.x); f[5] = f2bf(wb.y); f[6] = f2bf(wb.z); f[7] = f2bf(wb.w);
        } else {
#pragma unroll
            for (int e = 0; e < 8; ++e) f[e] = 0;
            f[0] = f2bf(b_ih[j] + b_hh[j]);
        }
        B2[t8] = f;
    }
    short8v xAc;                         // bias-row fragment (lanes g==1)
#pragma unroll
    for (int e = 0; e < 8; ++e) xAc[e] = 0;
    xAc[0] = (short)0x3F80;

    f32x16 zc;
#pragma unroll
    for (int e = 0; e < 16; ++e) zc[e] = 0.f;

    {
        short8v zv;
#pragma unroll
        for (int e = 0; e < 8; ++e) zv[e] = 0;
#pragma unroll
        for (int i = l; i < 256; i += 64) ((short8v*)Hl)[i] = zv;
    }
    float cst[2][4];
#pragma unroll
    for (int jt = 0; jt < 2; ++jt)
#pragma unroll
        for (int r = 0; r < 4; ++r) cst[jt][r] = 0.f;

    __syncthreads();

    const bool xld = (g == 0) && (lm < LNB_);     // only valid A rows load x
    const float* xbase = xdyn + (long)(nbase + (lm & (LNB_ - 1))) * T_ * 8;
    float4 xp0 = make_float4(0, 0, 0, 0), xp1 = make_float4(0, 0, 0, 0);
    if (xld) { xp0 = *(const float4*)xbase; xp1 = *(const float4*)(xbase + 4); }

    for (int t = 0; t < T_; ++t) {
        short8v xA;
        if (g == 0) {
            if (xld) {
                xA[0] = f2bf(xp0.x); xA[1] = f2bf(xp0.y); xA[2] = f2bf(xp0.z); xA[3] = f2bf(xp0.w);
                xA[4] = f2bf(xp1.x); xA[5] = f2bf(xp1.y); xA[6] = f2bf(xp1.z); xA[7] = f2bf(xp1.w);
                if (t < T_ - 1) {
                    xp0 = *(const float4*)(xbase + (t + 1) * 8);
                    xp1 = *(const float4*)(xbase + (t + 1) * 8 + 4);
                }
            } else {
#pragma unroll
                for (int e = 0; e < 8; ++e) xA[e] = 0;
            }
        } else xA = xAc;

        f32x16 acc[8];
#pragma unroll
        for (int t8 = 0; t8 < 8; ++t8)
            acc[t8] = __builtin_amdgcn_mfma_f32_32x32x16_bf16(xA, B2[t8], zc, 0, 0, 0);

        short8v hA[4];
#pragma unroll
        for (int ks = 0; ks < 4; ++ks) {
            int raddr = (lm * 128 + 32 * ks + 16 * g) ^ ((lm & 7) << 4);
            hA[ks] = *(const short8v*)(Hb + raddr);
        }
#pragma unroll
        for (int ks = 0; ks < 4; ++ks)
#pragma unroll
            for (int t8 = 0; t8 < 8; ++t8)
                acc[t8] = __builtin_amdgcn_mfma_f32_32x32x16_bf16(hA[ks], Bh[t8][ks], acc[t8], 0, 0, 0);

        __syncthreads();

        // only C rows mrow = r + 4g (r<4) < 8 are valid nodes
#pragma unroll
        for (int jt = 0; jt < 2; ++jt) {
#pragma unroll
            for (int r = 0; r < 4; ++r) {
                float iv = acc[jt][r];
                float fv = acc[2 + jt][r];
                float gv = acc[4 + jt][r];
                float ov = acc[6 + jt][r];
                float si = sigf(iv), sf = sigf(fv), tg = tanhfast(gv), so = sigf(ov);
                float cn = sf * cst[jt][r] + si * tg;
                cst[jt][r] = cn;
                float hn = so * tanhfast(cn);
                int mrow = r + 4 * g;
                int j = 32 * jt + lm;
                int waddr = (mrow * 128 + j * 2) ^ ((mrow & 7) << 4);
                *(short*)(Hb + waddr) = f2bf(hn);
                if (t == T_ - 1) hlast[(long)(nbase + mrow) * 64 + j] = hn;
            }
        }
        __syncthreads();
    }
}

// ---------- head: BN-relu(x1) ++ h_last -> hidden -> out ----------
__global__ __launch_bounds__(256) void k_head(
    const float* __restrict__ x1, const float* __restrict__ hlast,
    const float* __restrict__ bnp, const float* __restrict__ W_hid,
    const float* __restrict__ b_hid, const float* __restrict__ W_out,
    const float* __restrict__ b_out, float* __restrict__ out) {
    int n = blockIdx.x * 256 + threadIdx.x;
    if (n >= N_) return;
    float comb[128];
#pragma unroll
    for (int i = 0; i < 64; ++i)
        comb[i] = fmaxf(x1[(long)n * 64 + i] * bnp[i] + bnp[64 + i], 0.f);
#pragma unroll
    for (int i = 0; i < 64; ++i) comb[64 + i] = hlast[(long)n * 64 + i];
    float o = b_out[0];
    for (int j = 0; j < 32; ++j) {
        float a = b_hid[j];
#pragma unroll
        for (int i = 0; i < 128; ++i) a += comb[i] * W_hid[i * 32 + j];
        o += fmaxf(a, 0.f) * W_out[j];
    }
    out[n] = o;
}

extern "C" void kernel_launch(void* const* d_in, const int* in_sizes, int n_in,
                              void* d_out, int out_size, void* d_ws, size_t ws_size,
                              hipStream_t stream) {
    const float* x_node   = (const float*)d_in[0];
    const float* ea       = (const float*)d_in[1];
    const float* xdyn     = (const float*)d_in[2];
    const int*   eidx     = (const int*)d_in[3];
    const float* W_lin    = (const float*)d_in[4];
    const float* W_edge   = (const float*)d_in[5];
    const float* att_src  = (const float*)d_in[6];
    const float* att_dst  = (const float*)d_in[7];
    const float* att_edge = (const float*)d_in[8];
    const float* gat_bias = (const float*)d_in[9];
    const float* bn_gamma = (const float*)d_in[10];
    const float* bn_beta  = (const float*)d_in[11];
    const float* W_ih     = (const float*)d_in[12];
    const float* W_hh     = (const float*)d_in[13];
    const float* b_ih     = (const float*)d_in[14];
    const float* b_hh     = (const float*)d_in[15];
    const float* W_hid    = (const float*)d_in[16];
    const float* b_hid    = (const float*)d_in[17];
    const float* W_out    = (const float*)d_in[18];
    const float* b_out    = (const float*)d_in[19];
    float* out = (float*)d_out;

    char* ws = (char*)d_ws;
    size_t off = 0;
    auto alloc = [&](size_t bytes) -> void* {
        void* p = ws + off;
        off = (off + bytes + 255) & ~(size_t)255;
        return p;
    };
    int*      flag  = (int*)alloc(4);
    float*    P     = (float*)alloc(256 * 4);
    float*    Q     = (float*)alloc(64 * 8 * 4);
    float*    bnp   = (float*)alloc(128 * 4);
    char*     zs    = ws + off;                       // ---- zero region start
    float*    bnsum = (float*)alloc(128 * 4);
    int*      degi  = (int*)alloc((size_t)N_ * 4);
    int*      cursor= (int*)alloc((size_t)N_ * 4);
    size_t zbytes = (size_t)((ws + off) - zs);        // ---- zero region end
    int*      offs  = (int*)alloc((size_t)N_ * 4);
    float4*   aebuf = (float4*)alloc((size_t)E_ * 16);
    int2*     csr   = (int2*)alloc((size_t)E_ * 8);
    float*    xh    = (float*)alloc((size_t)N_ * 256 * 4);
    float*    asrc  = (float*)alloc((size_t)N_ * 4 * 4);
    float*    adst  = (float*)alloc((size_t)N_ * 4 * 4);
    float*    x1    = (float*)alloc((size_t)N_ * 64 * 4);
    float*    hlast = (float*)alloc((size_t)N_ * 64 * 4);
    (void)ws_size; (void)in_sizes; (void)n_in; (void)out_size;

    hipMemsetAsync(zs, 0, zbytes, stream);
    k_detect<<<1, 64, 0, stream>>>(eidx, flag);
    k_Pq<<<1, 256, 0, stream>>>(W_edge, att_edge, att_src, att_dst, W_lin, P, Q);
    k_node<<<N_ / 16, 256, 0, stream>>>(x_node, W_lin, Q, xh, asrc, adst);
    k_e1<<<(E_ + 255) / 256, 256, 0, stream>>>(eidx, flag, ea, P, aebuf, degi);
    k_scan<<<1, 256, 0, stream>>>(degi, offs);
    k_e2<<<(E_ + 255) / 256, 256, 0, stream>>>(eidx, flag, offs, cursor, csr);
    k_n2<<<(N_ + 3) / 4, 256, 0, stream>>>(offs, degi, csr, aebuf,
                                           (const float4*)asrc, (const float4*)adst,
                                           xh, gat_bias, x1);
    k_x1stats<<<128, 256, 0, stream>>>(x1, bnsum);
    k_bnfin<<<1, 64, 0, stream>>>(bnsum, bn_gamma, bn_beta, bnp);
    k_lstm_mfma<<<(N_ + LNB_ - 1) / LNB_, 64, 0, stream>>>(xdyn, W_ih, W_hh, b_ih, b_hh, hlast);
    k_head<<<(N_ + 255) / 256, 256, 0, stream>>>(x1, hlast, bnp, W_hid, b_hid, W_out, b_out, out);
}

// Round 9
// 428.390 us; speedup vs baseline: 4.4994x; 1.0964x over previous
//
#include <hip/hip_runtime.h>
#include <hip/hip_bf16.h>

constexpr int N_  = 20000;
constexpr int E_  = 320000;
constexpr int T_  = 24;
constexpr float NEG_ = 0.2f;
constexpr float EPS_ = 1e-5f;
constexpr int MAXD_ = 128;              // LDS edge-cache per node (fallback past this)
constexpr int LNB_ = 8;                 // nodes per wave in LSTM

typedef __attribute__((ext_vector_type(8)))  short short8v;
typedef __attribute__((ext_vector_type(16))) float f32x16;

// ---------- edge_index accessors (int32 vs int64 runtime-detected) ----------
__device__ __forceinline__ int esrc(const int* __restrict__ p, int e, int f64) {
    return f64 ? p[4 * e] : p[2 * e];
}
__device__ __forceinline__ int edst(const int* __restrict__ p, int e, int f64) {
    return f64 ? p[4 * e + 2] : p[2 * e + 1];
}

// fast gate math: v_rcp_f32 (1 ulp) instead of full-precision f32 division
__device__ __forceinline__ float sigf(float x) {
    return __builtin_amdgcn_rcpf(1.f + __expf(-x));
}
__device__ __forceinline__ float tanhfast(float x) {
    return 1.f - 2.f * __builtin_amdgcn_rcpf(1.f + __expf(2.f * x));
}

// f32 -> bf16 round-to-nearest-even
__device__ __forceinline__ short f2bf(float f) {
    union { float f; unsigned u; } v; v.f = f;
    unsigned r = v.u + 0x7FFFu + ((v.u >> 16) & 1u);
    return (short)(r >> 16);
}

// ---------- detect int64 vs int32 edge_index ----------
__global__ void k_detect(const int* __restrict__ idx, int* __restrict__ flag) {
    int v = idx[2 * threadIdx.x + 1];
    unsigned long long b = __ballot(v != 0);
    if (threadIdx.x == 0) flag[0] = (b == 0ULL) ? 1 : 0;
}

// ---------- P[k][h] = P^T precompute ; Q[k][q] = att projections of W_lin ----------
__global__ __launch_bounds__(256) void k_Pq(
    const float* __restrict__ W_edge, const float* __restrict__ att_edge,
    const float* __restrict__ att_src, const float* __restrict__ att_dst,
    const float* __restrict__ W_lin, float* __restrict__ P, float* __restrict__ Q) {
    int t = threadIdx.x;
    if (t < 64) {
        int k = t >> 2, h = t & 3;
        float s = 0.f;
        for (int c = 0; c < 64; ++c) s += W_edge[k * 256 + h * 64 + c] * att_edge[h * 64 + c];
        P[k * 4 + h] = s;
    }
    {
        int k = t >> 2, h = t & 3;      // k 0..63
        float s = 0.f, d = 0.f;
        for (int c = 0; c < 64; ++c) {
            float w = W_lin[k * 256 + h * 64 + c];
            s += w * att_src[h * 64 + c];
            d += w * att_dst[h * 64 + c];
        }
        Q[k * 8 + h] = s;
        Q[k * 8 + 4 + h] = d;
    }
}

// ---------- per-node: xh = x @ W_lin ; a_src/a_dst = x @ Q (16 nodes/block) ----------
__global__ __launch_bounds__(256) void k_node(
    const float* __restrict__ x, const float* __restrict__ W_lin,
    const float* __restrict__ Q,
    float* __restrict__ xh, float* __restrict__ asrc, float* __restrict__ adst) {
    __shared__ float xs[16][65];
    __shared__ float Qsh[64][8];
    int t = threadIdx.x;
    int nb = blockIdx.x * 16;
    for (int i = t; i < 16 * 64; i += 256) xs[i >> 6][i & 63] = x[(long)nb * 64 + i];
    for (int i = t; i < 64 * 8; i += 256) ((float*)Qsh)[i] = Q[i];
    __syncthreads();
    float acc[16];
#pragma unroll
    for (int m = 0; m < 16; ++m) acc[m] = 0.f;
    for (int k = 0; k < 64; ++k) {
        float w = W_lin[k * 256 + t];
#pragma unroll
        for (int m = 0; m < 16; ++m) acc[m] += xs[m][k] * w;
    }
#pragma unroll
    for (int m = 0; m < 16; ++m) xh[(long)(nb + m) * 256 + t] = acc[m];
    if (t < 128) {
        int m = t >> 3, q = t & 7;      // q: 0-3 src head, 4-7 dst head
        float s = 0.f;
        for (int k = 0; k < 64; ++k) s += xs[m][k] * Qsh[k][q];
        if (q < 4) asrc[(nb + m) * 4 + q] = s;
        else       adst[(nb + m) * 4 + (q - 4)] = s;
    }
}

// ---------- E1: ae[e][h] = P^T . ea[e] ; deg count ----------
__global__ __launch_bounds__(256) void k_e1(
    const int* __restrict__ idx, const int* __restrict__ flag,
    const float* __restrict__ ea, const float* __restrict__ P,
    float4* __restrict__ aebuf, int* __restrict__ degi) {
    __shared__ float Ps[256];
    int t = threadIdx.x;
    if (t < 64) Ps[t] = P[t];
    __syncthreads();
    int e = blockIdx.x * 256 + t;
    if (e >= E_) return;
    int f64 = flag[0];
    int d = edst(idx, e, f64);
    const float* ep = ea + (long)e * 16;
    float ae[4] = {0.f, 0.f, 0.f, 0.f};
#pragma unroll
    for (int k = 0; k < 16; ++k) {
        float v = ep[k];
#pragma unroll
        for (int h = 0; h < 4; ++h) ae[h] += v * Ps[k * 4 + h];
    }
    aebuf[e] = make_float4(ae[0], ae[1], ae[2], ae[3]);
    atomicAdd(&degi[d], 1);
}

// ---------- exclusive prefix scan of degi (single block) ----------
__global__ __launch_bounds__(256) void k_scan(const int* __restrict__ degi,
                                              int* __restrict__ offs) {
    __shared__ int part[256];
    int t = threadIdx.x;
    int base = t * 80;
    int s = 0;
    for (int i = 0; i < 80; ++i) { int ix = base + i; if (ix < N_) s += degi[ix]; }
    part[t] = s;
    __syncthreads();
    for (int d = 1; d < 256; d <<= 1) {
        int v = (t >= d) ? part[t - d] : 0;
        __syncthreads();
        part[t] += v;
        __syncthreads();
    }
    int run = (t > 0) ? part[t - 1] : 0;
    for (int i = 0; i < 80; ++i) {
        int ix = base + i;
        if (ix < N_) { offs[ix] = run; run += degi[ix]; }
    }
}

// ---------- E2: counting-sort edges into CSR (slot -> (edge, src)) ----------
__global__ __launch_bounds__(256) void k_e2(
    const int* __restrict__ idx, const int* __restrict__ flag,
    const int* __restrict__ offs, int* __restrict__ cursor,
    int2* __restrict__ csr) {
    int e = blockIdx.x * 256 + threadIdx.x;
    if (e >= E_) return;
    int f64 = flag[0];
    int d = edst(idx, e, f64);
    int s = esrc(idx, e, f64);
    int pos = atomicAdd(&cursor[d], 1);
    csr[offs[d] + pos] = make_int2(e, s);
}

// ---------- N2: per-dst softmax + gather (no atomics), fused x1 epilogue ----------
__global__ __launch_bounds__(256) void k_n2(
    const int* __restrict__ offs, const int* __restrict__ degi,
    const int2* __restrict__ csr, const float4* __restrict__ aebuf,
    const float4* __restrict__ asrc4, const float4* __restrict__ adst4,
    const float* __restrict__ xh, const float* __restrict__ gat_bias,
    float* __restrict__ x1) {
    __shared__ int   sS[4][MAXD_];
    __shared__ float4 sEx[4][MAXD_];
    int t = threadIdx.x, w = t >> 6, lane = t & 63;
    int n = blockIdx.x * 4 + w;
    if (n >= N_) return;
    int deg = degi[n], off = offs[n];
    float4 ad = adst4[n];

    float4 aesum = make_float4(0, 0, 0, 0), den = make_float4(0, 0, 0, 0);
    for (int base = 0; base < deg; base += 64) {
        int i = base + lane;
        if (i < deg) {
            int2 pr = csr[off + i];
            float4 ae = aebuf[pr.x];
            float4 as = asrc4[pr.y];
            float a0 = as.x + ad.x + ae.x; a0 = a0 > 0.f ? a0 : NEG_ * a0;
            float a1 = as.y + ad.y + ae.y; a1 = a1 > 0.f ? a1 : NEG_ * a1;
            float a2 = as.z + ad.z + ae.z; a2 = a2 > 0.f ? a2 : NEG_ * a2;
            float a3 = as.w + ad.w + ae.w; a3 = a3 > 0.f ? a3 : NEG_ * a3;
            float4 ex = make_float4(__expf(a0), __expf(a1), __expf(a2), __expf(a3));
            aesum.x += ae.x; aesum.y += ae.y; aesum.z += ae.z; aesum.w += ae.w;
            den.x += ex.x; den.y += ex.y; den.z += ex.z; den.w += ex.w;
            if (i < MAXD_) { sS[w][i] = pr.y; sEx[w][i] = ex; }
        }
    }
#pragma unroll
    for (int m = 32; m >= 1; m >>= 1) {
        aesum.x += __shfl_xor(aesum.x, m); aesum.y += __shfl_xor(aesum.y, m);
        aesum.z += __shfl_xor(aesum.z, m); aesum.w += __shfl_xor(aesum.w, m);
        den.x += __shfl_xor(den.x, m); den.y += __shfl_xor(den.y, m);
        den.z += __shfl_xor(den.z, m); den.w += __shfl_xor(den.w, m);
    }
    float dv = fmaxf((float)deg, 1.f);
    float4 as = asrc4[n];
    float a0 = as.x + ad.x + aesum.x / dv; a0 = a0 > 0.f ? a0 : NEG_ * a0;
    float a1 = as.y + ad.y + aesum.y / dv; a1 = a1 > 0.f ? a1 : NEG_ * a1;
    float a2 = as.z + ad.z + aesum.z / dv; a2 = a2 > 0.f ? a2 : NEG_ * a2;
    float a3 = as.w + ad.w + aesum.w / dv; a3 = a3 > 0.f ? a3 : NEG_ * a3;
    float4 exs = make_float4(__expf(a0), __expf(a1), __expf(a2), __expf(a3));
    den.x += exs.x; den.y += exs.y; den.z += exs.z; den.w += exs.w;
    float i0 = 1.f / (den.x + 1e-16f), i1 = 1.f / (den.y + 1e-16f);
    float i2 = 1.f / (den.z + 1e-16f), i3 = 1.f / (den.w + 1e-16f);
    __syncthreads();

    float acc = 0.f;
    for (int i = 0; i < deg; ++i) {
        int s; float4 ex;
        if (i < MAXD_) { s = sS[w][i]; ex = sEx[w][i]; }
        else {
            int2 pr = csr[off + i];
            s = pr.y;
            float4 ae = aebuf[pr.x];
            float4 a5 = asrc4[s];
            float b0 = a5.x + ad.x + ae.x; b0 = b0 > 0.f ? b0 : NEG_ * b0;
            float b1 = a5.y + ad.y + ae.y; b1 = b1 > 0.f ? b1 : NEG_ * b1;
            float b2 = a5.z + ad.z + ae.z; b2 = b2 > 0.f ? b2 : NEG_ * b2;
            float b3 = a5.w + ad.w + ae.w; b3 = b3 > 0.f ? b3 : NEG_ * b3;
            ex = make_float4(__expf(b0), __expf(b1), __expf(b2), __expf(b3));
        }
        const float* xp = xh + (long)s * 256;
        acc += ex.x * i0 * xp[lane] + ex.y * i1 * xp[64 + lane]
             + ex.z * i2 * xp[128 + lane] + ex.w * i3 * xp[192 + lane];
    }
    {
        const float* xp = xh + (long)n * 256;
        acc += exs.x * i0 * xp[lane] + exs.y * i1 * xp[64 + lane]
             + exs.z * i2 * xp[128 + lane] + exs.w * i3 * xp[192 + lane];
    }
    x1[(long)n * 64 + lane] = acc * 0.25f + gat_bias[lane];
}

// ---------- BN stats (read-only) ----------
__global__ __launch_bounds__(256) void k_x1stats(
    const float* __restrict__ x1, float* __restrict__ bnsum) {
    int c = threadIdx.x & 63, r = threadIdx.x >> 6;
    float s = 0.f, s2 = 0.f;
    for (int n = blockIdx.x * 4 + r; n < N_; n += gridDim.x * 4) {
        float v = x1[(long)n * 64 + c];
        s += v; s2 += v * v;
    }
    __shared__ float red[4][128];
    red[r][c] = s; red[r][64 + c] = s2;
    __syncthreads();
    if (r == 0) {
        float ts = red[0][c] + red[1][c] + red[2][c] + red[3][c];
        float t2 = red[0][64 + c] + red[1][64 + c] + red[2][64 + c] + red[3][64 + c];
        atomicAdd(&bnsum[c], ts);
        atomicAdd(&bnsum[64 + c], t2);
    }
}

__global__ void k_bnfin(const float* __restrict__ bnsum, const float* __restrict__ gamma,
                        const float* __restrict__ beta, float* __restrict__ bnp) {
    int c = threadIdx.x;
    float mu = bnsum[c] / (float)N_;
    float var = bnsum[64 + c] / (float)N_ - mu * mu;
    float sc = gamma[c] * rsqrtf(var + EPS_);
    bnp[c] = sc;
    bnp[64 + c] = beta[c] - mu * sc;
}

// ---------- LSTM via MFMA: 4 waves/block, W in LDS, 8 nodes/wave ----------
// Per wave: gates[32 x 256] = [h(64) | x(8),1,pad] @ [W_hh^T ; W_ih^T ; bias].
// W fragments live in block-shared LDS (re-read per step) so acc[8] fits in
// <=256 VGPR -> 2 waves/SIMD. No per-step barriers (H regions wave-private).
__global__ __launch_bounds__(256, 2) void k_lstm_mfma(
    const float* __restrict__ xdyn, const float* __restrict__ W_ih,
    const float* __restrict__ W_hh, const float* __restrict__ b_ih,
    const float* __restrict__ b_hh, float* __restrict__ hlast) {
    __shared__ char lds[57344];          // Wb 32K | W2 8K | H 4x4K
    char* W2b = lds + 32768;
    int t = threadIdx.x;
    int w = t >> 6, l = t & 63;
    int lm = l & 31, g = l >> 5;

    // ---- stage Wb: fragment (t8,ks), lane ll: W_hh[32*t8+(ll&31)][16*ks+8*(ll>>5)+e]
    for (int idx = t; idx < 2048; idx += 256) {
        int ll = idx & 63, ks = (idx >> 6) & 3, t8 = idx >> 8;
        int j = 32 * t8 + (ll & 31);
        const float* wp = W_hh + j * 64 + 16 * ks + 8 * (ll >> 5);
        float4 wa = *(const float4*)wp;
        float4 wb = *(const float4*)(wp + 4);
        short8v f;
        f[0] = f2bf(wa.x); f[1] = f2bf(wa.y); f[2] = f2bf(wa.z); f[3] = f2bf(wa.w);
        f[4] = f2bf(wb.x); f[5] = f2bf(wb.y); f[6] = f2bf(wb.z); f[7] = f2bf(wb.w);
        *(short8v*)(lds + idx * 16) = f;
    }
    // ---- stage W2: fragment t8, lane ll: g==0 -> W_ih row; g==1 -> bias row
    for (int idx = t; idx < 512; idx += 256) {
        int ll = idx & 63, t8 = idx >> 6;
        int j = 32 * t8 + (ll & 31);
        short8v f;
        if (ll < 32) {
            const float* wp = W_ih + j * 8;
            float4 wa = *(const float4*)wp;
            float4 wb = *(const float4*)(wp + 4);
            f[0] = f2bf(wa.x); f[1] = f2bf(wa.y); f[2] = f2bf(wa.z); f[3] = f2bf(wa.w);
            f[4] = f2bf(wb.x); f[5] = f2bf(wb.y); f[6] = f2bf(wb.z); f[7] = f2bf(wb.w);
        } else {
#pragma unroll
            for (int e = 0; e < 8; ++e) f[e] = 0;
            f[0] = f2bf(b_ih[j] + b_hh[j]);
        }
        *(short8v*)(W2b + idx * 16) = f;
    }
    // ---- zero wave-private H
    char* Hb = lds + 40960 + w * 4096;
    {
        short8v zv;
#pragma unroll
        for (int e = 0; e < 8; ++e) zv[e] = 0;
#pragma unroll
        for (int i = l; i < 256; i += 64) ((short8v*)Hb)[i] = zv;
    }
    __syncthreads();                     // one barrier; waves free-run after

    const int nbase = blockIdx.x * 32 + w * LNB_;
    f32x16 zc;
#pragma unroll
    for (int e = 0; e < 16; ++e) zc[e] = 0.f;
    short8v xAc;                         // bias-row A fragment (g==1)
#pragma unroll
    for (int e = 0; e < 8; ++e) xAc[e] = 0;
    xAc[0] = (short)0x3F80;
    float cst[2][4];
#pragma unroll
    for (int jt = 0; jt < 2; ++jt)
#pragma unroll
        for (int r = 0; r < 4; ++r) cst[jt][r] = 0.f;

    const bool xld = (g == 0) && (lm < LNB_);
    const float* xbase = xdyn + (long)(nbase + (lm & (LNB_ - 1))) * T_ * 8;
    float4 xp0 = make_float4(0, 0, 0, 0), xp1 = make_float4(0, 0, 0, 0);
    if (xld) { xp0 = *(const float4*)xbase; xp1 = *(const float4*)(xbase + 4); }

    for (int t_ = 0; t_ < T_; ++t_) {
        short8v xA;
        if (g == 0) {
            if (xld) {
                xA[0] = f2bf(xp0.x); xA[1] = f2bf(xp0.y); xA[2] = f2bf(xp0.z); xA[3] = f2bf(xp0.w);
                xA[4] = f2bf(xp1.x); xA[5] = f2bf(xp1.y); xA[6] = f2bf(xp1.z); xA[7] = f2bf(xp1.w);
                if (t_ < T_ - 1) {
                    xp0 = *(const float4*)(xbase + (t_ + 1) * 8);
                    xp1 = *(const float4*)(xbase + (t_ + 1) * 8 + 4);
                }
            } else {
#pragma unroll
                for (int e = 0; e < 8; ++e) xA[e] = 0;
            }
        } else xA = xAc;

        short8v hA[4];
#pragma unroll
        for (int ks = 0; ks < 4; ++ks) {
            int raddr = (lm * 128 + 32 * ks + 16 * g) ^ ((lm & 7) << 4);
            hA[ks] = *(const short8v*)(Hb + raddr);
        }

        f32x16 acc[8];
#pragma unroll
        for (int t8 = 0; t8 < 8; ++t8) {
            short8v b2f = *(const short8v*)(W2b + (t8 * 64 + l) * 16);
            acc[t8] = __builtin_amdgcn_mfma_f32_32x32x16_bf16(xA, b2f, zc, 0, 0, 0);
        }
#pragma unroll
        for (int ks = 0; ks < 4; ++ks)
#pragma unroll
            for (int t8 = 0; t8 < 8; ++t8) {
                short8v bh = *(const short8v*)(lds + ((t8 * 4 + ks) * 64 + l) * 16);
                acc[t8] = __builtin_amdgcn_mfma_f32_32x32x16_bf16(hA[ks], bh, acc[t8], 0, 0, 0);
            }

        // only C rows mrow = r + 4g (r<4) < 8 are valid nodes
#pragma unroll
        for (int jt = 0; jt < 2; ++jt) {
#pragma unroll
            for (int r = 0; r < 4; ++r) {
                float iv = acc[jt][r];
                float fv = acc[2 + jt][r];
                float gv = acc[4 + jt][r];
                float ov = acc[6 + jt][r];
                float si = sigf(iv), sf = sigf(fv), tg = tanhfast(gv), so = sigf(ov);
                float cn = sf * cst[jt][r] + si * tg;
                cst[jt][r] = cn;
                float hn = so * tanhfast(cn);
                int mrow = r + 4 * g;
                int j = 32 * jt + lm;
                int waddr = (mrow * 128 + j * 2) ^ ((mrow & 7) << 4);
                *(short*)(Hb + waddr) = f2bf(hn);
                if (t_ == T_ - 1) hlast[(long)(nbase + mrow) * 64 + j] = hn;
            }
        }
    }
}

// ---------- head: BN-relu(x1) ++ h_last -> hidden -> out ----------
__global__ __launch_bounds__(256) void k_head(
    const float* __restrict__ x1, const float* __restrict__ hlast,
    const float* __restrict__ bnp, const float* __restrict__ W_hid,
    const float* __restrict__ b_hid, const float* __restrict__ W_out,
    const float* __restrict__ b_out, float* __restrict__ out) {
    int n = blockIdx.x * 256 + threadIdx.x;
    if (n >= N_) return;
    float comb[128];
#pragma unroll
    for (int i = 0; i < 64; ++i)
        comb[i] = fmaxf(x1[(long)n * 64 + i] * bnp[i] + bnp[64 + i], 0.f);
#pragma unroll
    for (int i = 0; i < 64; ++i) comb[64 + i] = hlast[(long)n * 64 + i];
    float o = b_out[0];
    for (int j = 0; j < 32; ++j) {
        float a = b_hid[j];
#pragma unroll
        for (int i = 0; i < 128; ++i) a += comb[i] * W_hid[i * 32 + j];
        o += fmaxf(a, 0.f) * W_out[j];
    }
    out[n] = o;
}

extern "C" void kernel_launch(void* const* d_in, const int* in_sizes, int n_in,
                              void* d_out, int out_size, void* d_ws, size_t ws_size,
                              hipStream_t stream) {
    const float* x_node   = (const float*)d_in[0];
    const float* ea       = (const float*)d_in[1];
    const float* xdyn     = (const float*)d_in[2];
    const int*   eidx     = (const int*)d_in[3];
    const float* W_lin    = (const float*)d_in[4];
    const float* W_edge   = (const float*)d_in[5];
    const float* att_src  = (const float*)d_in[6];
    const float* att_dst  = (const float*)d_in[7];
    const float* att_edge = (const float*)d_in[8];
    const float* gat_bias = (const float*)d_in[9];
    const float* bn_gamma = (const float*)d_in[10];
    const float* bn_beta  = (const float*)d_in[11];
    const float* W_ih     = (const float*)d_in[12];
    const float* W_hh     = (const float*)d_in[13];
    const float* b_ih     = (const float*)d_in[14];
    const float* b_hh     = (const float*)d_in[15];
    const float* W_hid    = (const float*)d_in[16];
    const float* b_hid    = (const float*)d_in[17];
    const float* W_out    = (const float*)d_in[18];
    const float* b_out    = (const float*)d_in[19];
    float* out = (float*)d_out;

    char* ws = (char*)d_ws;
    size_t off = 0;
    auto alloc = [&](size_t bytes) -> void* {
        void* p = ws + off;
        off = (off + bytes + 255) & ~(size_t)255;
        return p;
    };
    int*      flag  = (int*)alloc(4);
    float*    P     = (float*)alloc(256 * 4);
    float*    Q     = (float*)alloc(64 * 8 * 4);
    float*    bnp   = (float*)alloc(128 * 4);
    char*     zs    = ws + off;                       // ---- zero region start
    float*    bnsum = (float*)alloc(128 * 4);
    int*      degi  = (int*)alloc((size_t)N_ * 4);
    int*      cursor= (int*)alloc((size_t)N_ * 4);
    size_t zbytes = (size_t)((ws + off) - zs);        // ---- zero region end
    int*      offs  = (int*)alloc((size_t)N_ * 4);
    float4*   aebuf = (float4*)alloc((size_t)E_ * 16);
    int2*     csr   = (int2*)alloc((size_t)E_ * 8);
    float*    xh    = (float*)alloc((size_t)N_ * 256 * 4);
    float*    asrc  = (float*)alloc((size_t)N_ * 4 * 4);
    float*    adst  = (float*)alloc((size_t)N_ * 4 * 4);
    float*    x1    = (float*)alloc((size_t)N_ * 64 * 4);
    float*    hlast = (float*)alloc((size_t)N_ * 64 * 4);
    (void)ws_size; (void)in_sizes; (void)n_in; (void)out_size;

    hipMemsetAsync(zs, 0, zbytes, stream);
    k_detect<<<1, 64, 0, stream>>>(eidx, flag);
    k_Pq<<<1, 256, 0, stream>>>(W_edge, att_edge, att_src, att_dst, W_lin, P, Q);
    k_node<<<N_ / 16, 256, 0, stream>>>(x_node, W_lin, Q, xh, asrc, adst);
    k_e1<<<(E_ + 255) / 256, 256, 0, stream>>>(eidx, flag, ea, P, aebuf, degi);
    k_scan<<<1, 256, 0, stream>>>(degi, offs);
    k_e2<<<(E_ + 255) / 256, 256, 0, stream>>>(eidx, flag, offs, cursor, csr);
    k_n2<<<(N_ + 3) / 4, 256, 0, stream>>>(offs, degi, csr, aebuf,
                                           (const float4*)asrc, (const float4*)adst,
                                           xh, gat_bias, x1);
    k_x1stats<<<128, 256, 0, stream>>>(x1, bnsum);
    k_bnfin<<<1, 64, 0, stream>>>(bnsum, bn_gamma, bn_beta, bnp);
    k_lstm_mfma<<<N_ / 32, 256, 0, stream>>>(xdyn, W_ih, W_hh, b_ih, b_hh, hlast);
    k_head<<<(N_ + 255) / 256, 256, 0, stream>>>(x1, hlast, bnp, W_hid, b_hid, W_out, b_out, out);
}

// Round 10
// 413.398 us; speedup vs baseline: 4.6626x; 1.0363x over previous
//
#include <hip/hip_runtime.h>
#include <hip/hip_bf16.h>

constexpr int N_  = 20000;
constexpr int E_  = 320000;
constexpr int T_  = 24;
constexpr float NEG_ = 0.2f;
constexpr float EPS_ = 1e-5f;
constexpr int MAXD_ = 128;              // LDS edge-cache per node (fallback past this)
constexpr int LNB_ = 8;                 // nodes per wave in LSTM

typedef __attribute__((ext_vector_type(8)))  short short8v;
typedef __attribute__((ext_vector_type(16))) float f32x16;

// ---------- edge_index accessors (int32 vs int64 runtime-detected) ----------
__device__ __forceinline__ int esrc(const int* __restrict__ p, int e, int f64) {
    return f64 ? p[4 * e] : p[2 * e];
}
__device__ __forceinline__ int edst(const int* __restrict__ p, int e, int f64) {
    return f64 ? p[4 * e + 2] : p[2 * e + 1];
}

// fast gate math: v_rcp_f32 (1 ulp) instead of full-precision f32 division
__device__ __forceinline__ float sigf(float x) {
    return __builtin_amdgcn_rcpf(1.f + __expf(-x));
}
__device__ __forceinline__ float tanhfast(float x) {
    return 1.f - 2.f * __builtin_amdgcn_rcpf(1.f + __expf(2.f * x));
}

// f32 -> bf16 round-to-nearest-even
__device__ __forceinline__ short f2bf(float f) {
    union { float f; unsigned u; } v; v.f = f;
    unsigned r = v.u + 0x7FFFu + ((v.u >> 16) & 1u);
    return (short)(r >> 16);
}
__device__ __forceinline__ float bf2f(unsigned short u) {
    return __uint_as_float((unsigned)u << 16);
}

// ---------- detect int64 vs int32 edge_index ----------
__global__ void k_detect(const int* __restrict__ idx, int* __restrict__ flag) {
    int v = idx[2 * threadIdx.x + 1];
    unsigned long long b = __ballot(v != 0);
    if (threadIdx.x == 0) flag[0] = (b == 0ULL) ? 1 : 0;
}

// ---------- P[k][h] = P^T precompute ; Q[k][q] = att projections of W_lin ----------
__global__ __launch_bounds__(256) void k_Pq(
    const float* __restrict__ W_edge, const float* __restrict__ att_edge,
    const float* __restrict__ att_src, const float* __restrict__ att_dst,
    const float* __restrict__ W_lin, float* __restrict__ P, float* __restrict__ Q) {
    int t = threadIdx.x;
    if (t < 64) {
        int k = t >> 2, h = t & 3;
        float s = 0.f;
        for (int c = 0; c < 64; ++c) s += W_edge[k * 256 + h * 64 + c] * att_edge[h * 64 + c];
        P[k * 4 + h] = s;
    }
    {
        int k = t >> 2, h = t & 3;      // k 0..63
        float s = 0.f, d = 0.f;
        for (int c = 0; c < 64; ++c) {
            float w = W_lin[k * 256 + h * 64 + c];
            s += w * att_src[h * 64 + c];
            d += w * att_dst[h * 64 + c];
        }
        Q[k * 8 + h] = s;
        Q[k * 8 + 4 + h] = d;
    }
}

// ---------- per-node: xh(bf16) = x @ W_lin ; a_src/a_dst = x @ Q ----------
__global__ __launch_bounds__(256) void k_node(
    const float* __restrict__ x, const float* __restrict__ W_lin,
    const float* __restrict__ Q,
    unsigned short* __restrict__ xhb, float* __restrict__ asrc, float* __restrict__ adst) {
    __shared__ float xs[16][65];
    __shared__ float Qsh[64][8];
    int t = threadIdx.x;
    int nb = blockIdx.x * 16;
    for (int i = t; i < 16 * 64; i += 256) xs[i >> 6][i & 63] = x[(long)nb * 64 + i];
    for (int i = t; i < 64 * 8; i += 256) ((float*)Qsh)[i] = Q[i];
    __syncthreads();
    float acc[16];
#pragma unroll
    for (int m = 0; m < 16; ++m) acc[m] = 0.f;
    for (int k = 0; k < 64; ++k) {
        float w = W_lin[k * 256 + t];
#pragma unroll
        for (int m = 0; m < 16; ++m) acc[m] += xs[m][k] * w;
    }
#pragma unroll
    for (int m = 0; m < 16; ++m) xhb[(long)(nb + m) * 256 + t] = (unsigned short)f2bf(acc[m]);
    if (t < 128) {
        int m = t >> 3, q = t & 7;      // q: 0-3 src head, 4-7 dst head
        float s = 0.f;
        for (int k = 0; k < 64; ++k) s += xs[m][k] * Qsh[k][q];
        if (q < 4) asrc[(nb + m) * 4 + q] = s;
        else       adst[(nb + m) * 4 + (q - 4)] = s;
    }
}

// ---------- E1: ae[e][h] = P^T . ea[e] ; deg count ----------
__global__ __launch_bounds__(256) void k_e1(
    const int* __restrict__ idx, const int* __restrict__ flag,
    const float* __restrict__ ea, const float* __restrict__ P,
    float4* __restrict__ aebuf, int* __restrict__ degi) {
    __shared__ float Ps[256];
    int t = threadIdx.x;
    if (t < 64) Ps[t] = P[t];
    __syncthreads();
    int e = blockIdx.x * 256 + t;
    if (e >= E_) return;
    int f64 = flag[0];
    int d = edst(idx, e, f64);
    const float* ep = ea + (long)e * 16;
    float ae[4] = {0.f, 0.f, 0.f, 0.f};
#pragma unroll
    for (int k = 0; k < 16; ++k) {
        float v = ep[k];
#pragma unroll
        for (int h = 0; h < 4; ++h) ae[h] += v * Ps[k * 4 + h];
    }
    aebuf[e] = make_float4(ae[0], ae[1], ae[2], ae[3]);
    atomicAdd(&degi[d], 1);
}

// ---------- exclusive prefix scan of degi (single block) ----------
__global__ __launch_bounds__(256) void k_scan(const int* __restrict__ degi,
                                              int* __restrict__ offs) {
    __shared__ int part[256];
    int t = threadIdx.x;
    int base = t * 80;
    int s = 0;
    for (int i = 0; i < 80; ++i) { int ix = base + i; if (ix < N_) s += degi[ix]; }
    part[t] = s;
    __syncthreads();
    for (int d = 1; d < 256; d <<= 1) {
        int v = (t >= d) ? part[t - d] : 0;
        __syncthreads();
        part[t] += v;
        __syncthreads();
    }
    int run = (t > 0) ? part[t - 1] : 0;
    for (int i = 0; i < 80; ++i) {
        int ix = base + i;
        if (ix < N_) { offs[ix] = run; run += degi[ix]; }
    }
}

// ---------- E2: counting-sort edges into CSR (slot -> (edge, src)) ----------
__global__ __launch_bounds__(256) void k_e2(
    const int* __restrict__ idx, const int* __restrict__ flag,
    const int* __restrict__ offs, int* __restrict__ cursor,
    int2* __restrict__ csr) {
    int e = blockIdx.x * 256 + threadIdx.x;
    if (e >= E_) return;
    int f64 = flag[0];
    int d = edst(idx, e, f64);
    int s = esrc(idx, e, f64);
    int pos = atomicAdd(&cursor[d], 1);
    csr[offs[d] + pos] = make_int2(e, s);
}

// ---------- N2: per-dst softmax + bf16 gather (no atomics) ----------
__global__ __launch_bounds__(256) void k_n2(
    const int* __restrict__ offs, const int* __restrict__ degi,
    const int2* __restrict__ csr, const float4* __restrict__ aebuf,
    const float4* __restrict__ asrc4, const float4* __restrict__ adst4,
    const unsigned short* __restrict__ xhb, const float* __restrict__ gat_bias,
    float* __restrict__ x1) {
    __shared__ int   sS[4][MAXD_];
    __shared__ float4 sEx[4][MAXD_];
    int t = threadIdx.x, w = t >> 6, lane = t & 63;
    int n = blockIdx.x * 4 + w;
    if (n >= N_) return;
    int deg = degi[n], off = offs[n];
    float4 ad = adst4[n];

    float4 aesum = make_float4(0, 0, 0, 0), den = make_float4(0, 0, 0, 0);
    for (int base = 0; base < deg; base += 64) {
        int i = base + lane;
        if (i < deg) {
            int2 pr = csr[off + i];
            float4 ae = aebuf[pr.x];
            float4 as = asrc4[pr.y];
            float a0 = as.x + ad.x + ae.x; a0 = a0 > 0.f ? a0 : NEG_ * a0;
            float a1 = as.y + ad.y + ae.y; a1 = a1 > 0.f ? a1 : NEG_ * a1;
            float a2 = as.z + ad.z + ae.z; a2 = a2 > 0.f ? a2 : NEG_ * a2;
            float a3 = as.w + ad.w + ae.w; a3 = a3 > 0.f ? a3 : NEG_ * a3;
            float4 ex = make_float4(__expf(a0), __expf(a1), __expf(a2), __expf(a3));
            aesum.x += ae.x; aesum.y += ae.y; aesum.z += ae.z; aesum.w += ae.w;
            den.x += ex.x; den.y += ex.y; den.z += ex.z; den.w += ex.w;
            if (i < MAXD_) { sS[w][i] = pr.y; sEx[w][i] = ex; }
        }
    }
#pragma unroll
    for (int m = 32; m >= 1; m >>= 1) {
        aesum.x += __shfl_xor(aesum.x, m); aesum.y += __shfl_xor(aesum.y, m);
        aesum.z += __shfl_xor(aesum.z, m); aesum.w += __shfl_xor(aesum.w, m);
        den.x += __shfl_xor(den.x, m); den.y += __shfl_xor(den.y, m);
        den.z += __shfl_xor(den.z, m); den.w += __shfl_xor(den.w, m);
    }
    float dv = fmaxf((float)deg, 1.f);
    float4 as = asrc4[n];
    float a0 = as.x + ad.x + aesum.x / dv; a0 = a0 > 0.f ? a0 : NEG_ * a0;
    float a1 = as.y + ad.y + aesum.y / dv; a1 = a1 > 0.f ? a1 : NEG_ * a1;
    float a2 = as.z + ad.z + aesum.z / dv; a2 = a2 > 0.f ? a2 : NEG_ * a2;
    float a3 = as.w + ad.w + aesum.w / dv; a3 = a3 > 0.f ? a3 : NEG_ * a3;
    float4 exs = make_float4(__expf(a0), __expf(a1), __expf(a2), __expf(a3));
    den.x += exs.x; den.y += exs.y; den.z += exs.z; den.w += exs.w;
    float i0 = 1.f / (den.x + 1e-16f), i1 = 1.f / (den.y + 1e-16f);
    float i2 = 1.f / (den.z + 1e-16f), i3 = 1.f / (den.w + 1e-16f);
    __syncthreads();

    float acc = 0.f;
#pragma unroll 2
    for (int i = 0; i < deg; ++i) {
        int s; float4 ex;
        if (i < MAXD_) { s = sS[w][i]; ex = sEx[w][i]; }
        else {
            int2 pr = csr[off + i];
            s = pr.y;
            float4 ae = aebuf[pr.x];
            float4 a5 = asrc4[s];
            float b0 = a5.x + ad.x + ae.x; b0 = b0 > 0.f ? b0 : NEG_ * b0;
            float b1 = a5.y + ad.y + ae.y; b1 = b1 > 0.f ? b1 : NEG_ * b1;
            float b2 = a5.z + ad.z + ae.z; b2 = b2 > 0.f ? b2 : NEG_ * b2;
            float b3 = a5.w + ad.w + ae.w; b3 = b3 > 0.f ? b3 : NEG_ * b3;
            ex = make_float4(__expf(b0), __expf(b1), __expf(b2), __expf(b3));
        }
        const unsigned short* xp = xhb + (long)s * 256;
        acc += ex.x * i0 * bf2f(xp[lane]) + ex.y * i1 * bf2f(xp[64 + lane])
             + ex.z * i2 * bf2f(xp[128 + lane]) + ex.w * i3 * bf2f(xp[192 + lane]);
    }
    {
        const unsigned short* xp = xhb + (long)n * 256;
        acc += exs.x * i0 * bf2f(xp[lane]) + exs.y * i1 * bf2f(xp[64 + lane])
             + exs.z * i2 * bf2f(xp[128 + lane]) + exs.w * i3 * bf2f(xp[192 + lane]);
    }
    x1[(long)n * 64 + lane] = acc * 0.25f + gat_bias[lane];
}

// ---------- BN stats (read-only) ----------
__global__ __launch_bounds__(256) void k_x1stats(
    const float* __restrict__ x1, float* __restrict__ bnsum) {
    int c = threadIdx.x & 63, r = threadIdx.x >> 6;
    float s = 0.f, s2 = 0.f;
    for (int n = blockIdx.x * 4 + r; n < N_; n += gridDim.x * 4) {
        float v = x1[(long)n * 64 + c];
        s += v; s2 += v * v;
    }
    __shared__ float red[4][128];
    red[r][c] = s; red[r][64 + c] = s2;
    __syncthreads();
    if (r == 0) {
        float ts = red[0][c] + red[1][c] + red[2][c] + red[3][c];
        float t2 = red[0][64 + c] + red[1][64 + c] + red[2][64 + c] + red[3][64 + c];
        atomicAdd(&bnsum[c], ts);
        atomicAdd(&bnsum[64 + c], t2);
    }
}

__global__ void k_bnfin(const float* __restrict__ bnsum, const float* __restrict__ gamma,
                        const float* __restrict__ beta, float* __restrict__ bnp) {
    int c = threadIdx.x;
    float mu = bnsum[c] / (float)N_;
    float var = bnsum[64 + c] / (float)N_ - mu * mu;
    float sc = gamma[c] * rsqrtf(var + EPS_);
    bnp[c] = sc;
    bnp[64 + c] = beta[c] - mu * sc;
}

// ---------- LSTM via MFMA: 4 waves/block, W in LDS, 8 nodes/wave ----------
__global__ __launch_bounds__(256, 2) void k_lstm_mfma(
    const float* __restrict__ xdyn, const float* __restrict__ W_ih,
    const float* __restrict__ W_hh, const float* __restrict__ b_ih,
    const float* __restrict__ b_hh, float* __restrict__ hlast) {
    __shared__ char lds[57344];          // Wb 32K | W2 8K | H 4x4K
    char* W2b = lds + 32768;
    int t = threadIdx.x;
    int w = t >> 6, l = t & 63;
    int lm = l & 31, g = l >> 5;

    for (int idx = t; idx < 2048; idx += 256) {
        int ll = idx & 63, ks = (idx >> 6) & 3, t8 = idx >> 8;
        int j = 32 * t8 + (ll & 31);
        const float* wp = W_hh + j * 64 + 16 * ks + 8 * (ll >> 5);
        float4 wa = *(const float4*)wp;
        float4 wb = *(const float4*)(wp + 4);
        short8v f;
        f[0] = f2bf(wa.x); f[1] = f2bf(wa.y); f[2] = f2bf(wa.z); f[3] = f2bf(wa.w);
        f[4] = f2bf(wb.x); f[5] = f2bf(wb.y); f[6] = f2bf(wb.z); f[7] = f2bf(wb.w);
        *(short8v*)(lds + idx * 16) = f;
    }
    for (int idx = t; idx < 512; idx += 256) {
        int ll = idx & 63, t8 = idx >> 6;
        int j = 32 * t8 + (ll & 31);
        short8v f;
        if (ll < 32) {
            const float* wp = W_ih + j * 8;
            float4 wa = *(const float4*)wp;
            float4 wb = *(const float4*)(wp + 4);
            f[0] = f2bf(wa.x); f[1] = f2bf(wa.y); f[2] = f2bf(wa.z); f[3] = f2bf(wa.w);
            f[4] = f2bf(wb.x); f[5] = f2bf(wb.y); f[6] = f2bf(wb.z); f[7] = f2bf(wb.w);
        } else {
#pragma unroll
            for (int e = 0; e < 8; ++e) f[e] = 0;
            f[0] = f2bf(b_ih[j] + b_hh[j]);
        }
        *(short8v*)(W2b + idx * 16) = f;
    }
    char* Hb = lds + 40960 + w * 4096;
    {
        short8v zv;
#pragma unroll
        for (int e = 0; e < 8; ++e) zv[e] = 0;
#pragma unroll
        for (int i = l; i < 256; i += 64) ((short8v*)Hb)[i] = zv;
    }
    __syncthreads();                     // one barrier; waves free-run after

    const int nbase = blockIdx.x * 32 + w * LNB_;
    f32x16 zc;
#pragma unroll
    for (int e = 0; e < 16; ++e) zc[e] = 0.f;
    short8v xAc;                         // bias-row A fragment (g==1)
#pragma unroll
    for (int e = 0; e < 8; ++e) xAc[e] = 0;
    xAc[0] = (short)0x3F80;
    float cst[2][4];
#pragma unroll
    for (int jt = 0; jt < 2; ++jt)
#pragma unroll
        for (int r = 0; r < 4; ++r) cst[jt][r] = 0.f;

    const bool xld = (g == 0) && (lm < LNB_);
    const float* xbase = xdyn + (long)(nbase + (lm & (LNB_ - 1))) * T_ * 8;
    float4 xp0 = make_float4(0, 0, 0, 0), xp1 = make_float4(0, 0, 0, 0);
    if (xld) { xp0 = *(const float4*)xbase; xp1 = *(const float4*)(xbase + 4); }

    for (int t_ = 0; t_ < T_; ++t_) {
        short8v xA;
        if (g == 0) {
            if (xld) {
                xA[0] = f2bf(xp0.x); xA[1] = f2bf(xp0.y); xA[2] = f2bf(xp0.z); xA[3] = f2bf(xp0.w);
                xA[4] = f2bf(xp1.x); xA[5] = f2bf(xp1.y); xA[6] = f2bf(xp1.z); xA[7] = f2bf(xp1.w);
                if (t_ < T_ - 1) {
                    xp0 = *(const float4*)(xbase + (t_ + 1) * 8);
                    xp1 = *(const float4*)(xbase + (t_ + 1) * 8 + 4);
                }
            } else {
#pragma unroll
                for (int e = 0; e < 8; ++e) xA[e] = 0;
            }
        } else xA = xAc;

        short8v hA[4];
#pragma unroll
        for (int ks = 0; ks < 4; ++ks) {
            int raddr = (lm * 128 + 32 * ks + 16 * g) ^ ((lm & 7) << 4);
            hA[ks] = *(const short8v*)(Hb + raddr);
        }

        f32x16 acc[8];
#pragma unroll
        for (int t8 = 0; t8 < 8; ++t8) {
            short8v b2f = *(const short8v*)(W2b + (t8 * 64 + l) * 16);
            acc[t8] = __builtin_amdgcn_mfma_f32_32x32x16_bf16(xA, b2f, zc, 0, 0, 0);
        }
#pragma unroll
        for (int ks = 0; ks < 4; ++ks)
#pragma unroll
            for (int t8 = 0; t8 < 8; ++t8) {
                short8v bh = *(const short8v*)(lds + ((t8 * 4 + ks) * 64 + l) * 16);
                acc[t8] = __builtin_amdgcn_mfma_f32_32x32x16_bf16(hA[ks], bh, acc[t8], 0, 0, 0);
            }

#pragma unroll
        for (int jt = 0; jt < 2; ++jt) {
#pragma unroll
            for (int r = 0; r < 4; ++r) {
                float iv = acc[jt][r];
                float fv = acc[2 + jt][r];
                float gv = acc[4 + jt][r];
                float ov = acc[6 + jt][r];
                float si = sigf(iv), sf = sigf(fv), tg = tanhfast(gv), so = sigf(ov);
                float cn = sf * cst[jt][r] + si * tg;
                cst[jt][r] = cn;
                float hn = so * tanhfast(cn);
                int mrow = r + 4 * g;
                int j = 32 * jt + lm;
                int waddr = (mrow * 128 + j * 2) ^ ((mrow & 7) << 4);
                *(short*)(Hb + waddr) = f2bf(hn);
                if (t_ == T_ - 1) hlast[(long)(nbase + mrow) * 64 + j] = hn;
            }
        }
    }
}

// ---------- head: BN-relu(x1) ++ h_last -> hidden -> out ----------
__global__ __launch_bounds__(256) void k_head(
    const float* __restrict__ x1, const float* __restrict__ hlast,
    const float* __restrict__ bnp, const float* __restrict__ W_hid,
    const float* __restrict__ b_hid, const float* __restrict__ W_out,
    const float* __restrict__ b_out, float* __restrict__ out) {
    int n = blockIdx.x * 256 + threadIdx.x;
    if (n >= N_) return;
    float comb[128];
#pragma unroll
    for (int i = 0; i < 64; ++i)
        comb[i] = fmaxf(x1[(long)n * 64 + i] * bnp[i] + bnp[64 + i], 0.f);
#pragma unroll
    for (int i = 0; i < 64; ++i) comb[64 + i] = hlast[(long)n * 64 + i];
    float o = b_out[0];
    for (int j = 0; j < 32; ++j) {
        float a = b_hid[j];
#pragma unroll
        for (int i = 0; i < 128; ++i) a += comb[i] * W_hid[i * 32 + j];
        o += fmaxf(a, 0.f) * W_out[j];
    }
    out[n] = o;
}

extern "C" void kernel_launch(void* const* d_in, const int* in_sizes, int n_in,
                              void* d_out, int out_size, void* d_ws, size_t ws_size,
                              hipStream_t stream) {
    const float* x_node   = (const float*)d_in[0];
    const float* ea       = (const float*)d_in[1];
    const float* xdyn     = (const float*)d_in[2];
    const int*   eidx     = (const int*)d_in[3];
    const float* W_lin    = (const float*)d_in[4];
    const float* W_edge   = (const float*)d_in[5];
    const float* att_src  = (const float*)d_in[6];
    const float* att_dst  = (const float*)d_in[7];
    const float* att_edge = (const float*)d_in[8];
    const float* gat_bias = (const float*)d_in[9];
    const float* bn_gamma = (const float*)d_in[10];
    const float* bn_beta  = (const float*)d_in[11];
    const float* W_ih     = (const float*)d_in[12];
    const float* W_hh     = (const float*)d_in[13];
    const float* b_ih     = (const float*)d_in[14];
    const float* b_hh     = (const float*)d_in[15];
    const float* W_hid    = (const float*)d_in[16];
    const float* b_hid    = (const float*)d_in[17];
    const float* W_out    = (const float*)d_in[18];
    const float* b_out    = (const float*)d_in[19];
    float* out = (float*)d_out;

    char* ws = (char*)d_ws;
    size_t off = 0;
    auto alloc = [&](size_t bytes) -> void* {
        void* p = ws + off;
        off = (off + bytes + 255) & ~(size_t)255;
        return p;
    };
    int*      flag  = (int*)alloc(4);
    float*    P     = (float*)alloc(256 * 4);
    float*    Q     = (float*)alloc(64 * 8 * 4);
    float*    bnp   = (float*)alloc(128 * 4);
    char*     zs    = ws + off;                       // ---- zero region start
    float*    bnsum = (float*)alloc(128 * 4);
    int*      degi  = (int*)alloc((size_t)N_ * 4);
    int*      cursor= (int*)alloc((size_t)N_ * 4);
    size_t zbytes = (size_t)((ws + off) - zs);        // ---- zero region end
    int*      offs  = (int*)alloc((size_t)N_ * 4);
    float4*   aebuf = (float4*)alloc((size_t)E_ * 16);
    int2*     csr   = (int2*)alloc((size_t)E_ * 8);
    unsigned short* xhb = (unsigned short*)alloc((size_t)N_ * 256 * 2);
    float*    asrc  = (float*)alloc((size_t)N_ * 4 * 4);
    float*    adst  = (float*)alloc((size_t)N_ * 4 * 4);
    float*    x1    = (float*)alloc((size_t)N_ * 64 * 4);
    float*    hlast = (float*)alloc((size_t)N_ * 64 * 4);
    (void)ws_size; (void)in_sizes; (void)n_in; (void)out_size;

    hipMemsetAsync(zs, 0, zbytes, stream);
    k_detect<<<1, 64, 0, stream>>>(eidx, flag);
    k_Pq<<<1, 256, 0, stream>>>(W_edge, att_edge, att_src, att_dst, W_lin, P, Q);
    k_node<<<N_ / 16, 256, 0, stream>>>(x_node, W_lin, Q, xhb, asrc, adst);
    k_e1<<<(E_ + 255) / 256, 256, 0, stream>>>(eidx, flag, ea, P, aebuf, degi);
    k_scan<<<1, 256, 0, stream>>>(degi, offs);
    k_e2<<<(E_ + 255) / 256, 256, 0, stream>>>(eidx, flag, offs, cursor, csr);
    k_n2<<<(N_ + 3) / 4, 256, 0, stream>>>(offs, degi, csr, aebuf,
                                           (const float4*)asrc, (const float4*)adst,
                                           xhb, gat_bias, x1);
    k_x1stats<<<128, 256, 0, stream>>>(x1, bnsum);
    k_bnfin<<<1, 64, 0, stream>>>(bnsum, bn_gamma, bn_beta, bnp);
    k_lstm_mfma<<<N_ / 32, 256, 0, stream>>>(xdyn, W_ih, W_hh, b_ih, b_hh, hlast);
    k_head<<<(N_ + 255) / 256, 256, 0, stream>>>(x1, hlast, bnp, W_hid, b_hid, W_out, b_out, out);
}